// Round 3
// baseline (8880.989 us; speedup 1.0000x reference)
//
#include <hip/hip_runtime.h>
#include <hip/hip_bf16.h>
#include <math.h>

#define N_ORIG 200000
#define NS_    500000
#define ES_    1000000
#define B_     256
#define P_     32
#define D_     128
#define BP_    8192
#define RW_    20
#define PRW_   8
#define TH_    64
#define CH_    512

static inline int cdiv_l(long a, long b){ return (int)((a + b - 1) / b); }

typedef unsigned short ushort_t;

__device__ __forceinline__ float b2f(ushort_t u){
    union { unsigned int i; float f; } c; c.i = ((unsigned int)u) << 16; return c.f;
}
__device__ __forceinline__ ushort_t f2b(float f){
    union { float f; unsigned int u; } c; c.f = f;
    unsigned int u = c.u;
    u += 0x7fffu + ((u >> 16) & 1u);      // RNE
    return (ushort_t)(u >> 16);
}
__device__ __forceinline__ float4 b2f4(ushort4 v){
    return make_float4(b2f(v.x), b2f(v.y), b2f(v.z), b2f(v.w));
}
__device__ __forceinline__ ushort4 f2b4(float4 v){
    ushort4 r; r.x = f2b(v.x); r.y = f2b(v.y); r.z = f2b(v.z); r.w = f2b(v.w); return r;
}

__device__ __forceinline__ float gelu_t(float x){
    float t = tanhf(0.7978845608028654f * (x + 0.044715f * x * x * x));
    return 0.5f * x * (1.0f + t);
}

// ---------------- diagnostics ----------------
__global__ void k_breadcrumb(float* __restrict__ out, int n, float v){
    int i = blockIdx.x * 256 + threadIdx.x;
    if (i < n) out[i] = v;
}

// ---------------- counts & CSR build ----------------
__global__ void k_counts(const int* __restrict__ bx, const int* __restrict__ nm,
                         int* __restrict__ pcnt, int* __restrict__ ncnt){
    int i = blockIdx.x * 256 + threadIdx.x;
    if (i >= NS_) return;
    atomicAdd(&pcnt[bx[i]], 1);
    atomicAdd(&ncnt[nm[i]], 1);
}

__global__ void k_deg(const int* __restrict__ dstv, int* __restrict__ deg){
    int e = blockIdx.x * 256 + threadIdx.x;
    if (e >= ES_) return;
    atomicAdd(&deg[dstv[e]], 1);
}

// block = 256 threads, 1024 elements; in-place exclusive scan of rp, block sums -> bsum
__global__ __launch_bounds__(256)
void k_scan1(int* __restrict__ rp, int* __restrict__ bsum){
    __shared__ int sb[256];
    int tid = threadIdx.x;
    long base = (long)blockIdx.x * 1024 + tid * 4;
    int v0 = 0, v1 = 0, v2 = 0, v3 = 0;
    if (base + 0 < NS_) v0 = rp[base + 0];
    if (base + 1 < NS_) v1 = rp[base + 1];
    if (base + 2 < NS_) v2 = rp[base + 2];
    if (base + 3 < NS_) v3 = rp[base + 3];
    int tsum = v0 + v1 + v2 + v3;
    sb[tid] = tsum;
    __syncthreads();
    for (int o = 1; o < 256; o <<= 1){
        int t = (tid >= o) ? sb[tid - o] : 0;
        __syncthreads();
        sb[tid] += t;
        __syncthreads();
    }
    int excl = sb[tid] - tsum;
    if (tid == 255) bsum[blockIdx.x] = sb[255];
    if (base + 0 < NS_) rp[base + 0] = excl;
    if (base + 1 < NS_) rp[base + 1] = excl + v0;
    if (base + 2 < NS_) rp[base + 2] = excl + v0 + v1;
    if (base + 3 < NS_) rp[base + 3] = excl + v0 + v1 + v2;
}

// single block, exclusive scan of nb (<=512) block sums, in place
__global__ __launch_bounds__(512)
void k_scan2(int* __restrict__ bsum, int nb){
    __shared__ int sb[512];
    int tid = threadIdx.x;
    int orig = (tid < nb) ? bsum[tid] : 0;
    sb[tid] = orig;
    __syncthreads();
    for (int o = 1; o < 512; o <<= 1){
        int t = (tid >= o) ? sb[tid - o] : 0;
        __syncthreads();
        sb[tid] += t;
        __syncthreads();
    }
    if (tid < nb) bsum[tid] = sb[tid] - orig;
}

__global__ void k_scan3(int* __restrict__ rp, const int* __restrict__ bsum,
                        int* __restrict__ cursor){
    long i = (long)blockIdx.x * 256 + threadIdx.x;
    if (i < NS_){
        int v = rp[i] + bsum[i >> 10];
        rp[i] = v;
        cursor[i] = v;
    } else if (i == NS_){
        rp[NS_] = ES_;
    }
}

__global__ void k_scatter(const int* __restrict__ srcv, const int* __restrict__ dstv,
                          const int* __restrict__ ea, const int* __restrict__ em,
                          int* __restrict__ cursor, int* __restrict__ epack){
    int e = blockIdx.x * 256 + threadIdx.x;
    if (e >= ES_) return;
    int pos = atomicAdd(&cursor[dstv[e]], 1);
    epack[pos] = srcv[e] | (ea[em[e]] << 20);
}

// ---------------- node encoder ----------------
__global__ void k_encode(const int* __restrict__ xa, const float* __restrict__ rw,
                         const float* __restrict__ aemb, const float* __restrict__ rwW,
                         const float* __restrict__ rwb, float* __restrict__ x0){
    int i = blockIdx.x * 256 + threadIdx.x;
    if (i >= N_ORIG * D_) return;
    int n = i >> 7, d = i & 127;
    float acc = aemb[xa[n] * D_ + d] + rwb[d];
    const float* r = rw + (long)n * RW_;
    #pragma unroll
    for (int k = 0; k < RW_; k++) acc = fmaf(r[k], rwW[k * D_ + d], acc);
    x0[i] = acc;
}

// ---------------- row-wise kernels (rows of 128; quarter-row per thread) ----------------
__global__ void k_gather_f2b(const float4* __restrict__ rows, const int* __restrict__ map,
                             ushort4* __restrict__ dst, int n){
    int i = blockIdx.x * 256 + threadIdx.x;
    if (i >= n * 32) return;
    dst[i] = f2b4(rows[(long)map[i >> 5] * 32 + (i & 31)]);
}

__global__ void k_gather_add_b(ushort4* __restrict__ x, const ushort4* __restrict__ rows,
                               const int* __restrict__ map, int n){
    int i = blockIdx.x * 256 + threadIdx.x;
    if (i >= n * 32) return;
    float4 v = b2f4(x[i]);
    float4 u = b2f4(rows[(long)map[i >> 5] * 32 + (i & 31)]);
    v.x += u.x; v.y += u.y; v.z += u.z; v.w += u.w;
    x[i] = f2b4(v);
}

__global__ void k_gather_div_b(ushort4* __restrict__ x, const float4* __restrict__ sums,
                               const int* __restrict__ cnt, const int* __restrict__ map, int n){
    int i = blockIdx.x * 256 + threadIdx.x;
    if (i >= n * 32) return;
    int nd = map[i >> 5];
    float c = fmaxf((float)cnt[nd], 1.0f);
    float4 v = sums[(long)nd * 32 + (i & 31)];
    v.x /= c; v.y /= c; v.z /= c; v.w /= c;
    x[i] = f2b4(v);
}

__global__ void k_seg_add_b(const ushort4* __restrict__ x, const int* __restrict__ idx,
                            float* __restrict__ out, int n){
    int i = blockIdx.x * 256 + threadIdx.x;
    if (i >= n * 32) return;
    int r = i >> 5, q = i & 31;
    float4 v = b2f4(x[i]);
    float* base = out + (long)idx[r] * D_ + q * 4;
    atomicAdd(base + 0, v.x);
    atomicAdd(base + 1, v.y);
    atomicAdd(base + 2, v.z);
    atomicAdd(base + 3, v.w);
}

__global__ void k_div_cnt4(float4* __restrict__ rows, const int* __restrict__ cnt, int n){
    int i = blockIdx.x * 256 + threadIdx.x;
    if (i >= n * 32) return;
    float c = fmaxf((float)cnt[i >> 5], 1.0f);
    float4 v = rows[i];
    v.x /= c; v.y /= c; v.z /= c; v.w /= c;
    rows[i] = v;
}

// ---------------- U-step GEMM: out_bf16 = relu(in_f32 @ W + b) ----------------
#define FMA4(AV, BV, AC) { AC[0]=fmaf(AV,BV.x,AC[0]); AC[1]=fmaf(AV,BV.y,AC[1]); AC[2]=fmaf(AV,BV.z,AC[2]); AC[3]=fmaf(AV,BV.w,AC[3]); }

__global__ __launch_bounds__(256)
void k_gemm128(const float* __restrict__ in1, const float* __restrict__ W,
               const float* __restrict__ bvec, ushort_t* __restrict__ out, int nrows){
    __shared__ ushort_t sW[D_ * D_];    // 32 KB
    __shared__ float sIn[16 * 132];     // 8.25 KB
    int tid = threadIdx.x;
    for (int k = tid; k < D_ * D_; k += 256) sW[k] = f2b(W[k]);
    int jc = (tid & 31) * 4;
    int rr = (tid >> 5) * 2;
    float4 bv = *(const float4*)&bvec[jc];
    const float4* in1_4 = (const float4*)in1;
    ushort4* out_4 = (ushort4*)out;
    int ntiles = (nrows + 15) / 16;
    for (int tile = blockIdx.x; tile < ntiles; tile += gridDim.x){
        int r0 = tile * 16;
        __syncthreads();
        for (int k = tid; k < 16 * 32; k += 256){
            int r = k >> 5, q = k & 31;
            float4 v = make_float4(0.f, 0.f, 0.f, 0.f);
            if (r0 + r < nrows) v = in1_4[(long)(r0 + r) * 32 + q];
            *(float4*)&sIn[r * 132 + q * 4] = v;
        }
        __syncthreads();
        float acc0[4] = {0.f,0.f,0.f,0.f}, acc1[4] = {0.f,0.f,0.f,0.f};
        for (int k = 0; k < D_; k += 4){
            float4 a0 = *(const float4*)&sIn[(rr + 0) * 132 + k];
            float4 a1 = *(const float4*)&sIn[(rr + 1) * 132 + k];
            float4 b0 = b2f4(*(const ushort4*)&sW[(k + 0) * D_ + jc]);
            float4 b1 = b2f4(*(const ushort4*)&sW[(k + 1) * D_ + jc]);
            float4 b2 = b2f4(*(const ushort4*)&sW[(k + 2) * D_ + jc]);
            float4 b3 = b2f4(*(const ushort4*)&sW[(k + 3) * D_ + jc]);
            FMA4(a0.x, b0, acc0) FMA4(a0.y, b1, acc0) FMA4(a0.z, b2, acc0) FMA4(a0.w, b3, acc0)
            FMA4(a1.x, b0, acc1) FMA4(a1.y, b1, acc1) FMA4(a1.z, b2, acc1) FMA4(a1.w, b3, acc1)
        }
        #define EPILOG(AC, ROFF) { \
            int row = r0 + rr + ROFF; \
            if (row < nrows){ \
                float4 o; \
                o.x = fmaxf(AC[0] + bv.x, 0.f); o.y = fmaxf(AC[1] + bv.y, 0.f); \
                o.z = fmaxf(AC[2] + bv.z, 0.f); o.w = fmaxf(AC[3] + bv.w, 0.f); \
                out_4[(long)row * 32 + (tid & 31)] = f2b4(o); \
            } }
        EPILOG(acc0, 0)
        EPILOG(acc1, 1)
        #undef EPILOG
    }
}

// ---------------- fused conv: xout = xin + relu((xin + agg_csr) @ W + b) ----------------
__global__ __launch_bounds__(256)
void k_gemm_conv(const ushort_t* __restrict__ xin, ushort_t* __restrict__ xout,
                 const int* __restrict__ rp, const int* __restrict__ epack,
                 const float* __restrict__ bond, const float* __restrict__ W,
                 const float* __restrict__ bvec){
    __shared__ ushort_t sW[D_ * D_];    // 32 KB
    __shared__ float sIn[16 * 132];     // 8.25 KB
    int tid = threadIdx.x;
    for (int k = tid; k < D_ * D_; k += 256) sW[k] = f2b(W[k]);
    int jc = (tid & 31) * 4;
    int rr = (tid >> 5) * 2;
    float4 bv = *(const float4*)&bvec[jc];
    const ushort4* xin4 = (const ushort4*)xin;
    ushort4* xout4 = (ushort4*)xout;
    const float4* bond4 = (const float4*)bond;
    const int ntiles = NS_ / 16;        // NS_ % 16 == 0
    for (int tile = blockIdx.x; tile < ntiles; tile += gridDim.x){
        int r0 = tile * 16;
        __syncthreads();
        for (int k = tid; k < 16 * 32; k += 256){
            int r = k >> 5, q = k & 31;
            int row = r0 + r;
            float4 v = b2f4(xin4[(long)row * 32 + q]);
            int e0 = rp[row], e1 = rp[row + 1];
            for (int e = e0; e < e1; e++){
                int pk = epack[e];
                float4 u = b2f4(xin4[(long)(pk & 0xFFFFF) * 32 + q]);
                float4 bb = bond4[(pk >> 20) * 32 + q];
                v.x += fmaxf(u.x + bb.x, 0.f);
                v.y += fmaxf(u.y + bb.y, 0.f);
                v.z += fmaxf(u.z + bb.z, 0.f);
                v.w += fmaxf(u.w + bb.w, 0.f);
            }
            *(float4*)&sIn[r * 132 + q * 4] = v;
        }
        __syncthreads();
        float acc0[4] = {0.f,0.f,0.f,0.f}, acc1[4] = {0.f,0.f,0.f,0.f};
        for (int k = 0; k < D_; k += 4){
            float4 a0 = *(const float4*)&sIn[(rr + 0) * 132 + k];
            float4 a1 = *(const float4*)&sIn[(rr + 1) * 132 + k];
            float4 b0 = b2f4(*(const ushort4*)&sW[(k + 0) * D_ + jc]);
            float4 b1 = b2f4(*(const ushort4*)&sW[(k + 1) * D_ + jc]);
            float4 b2 = b2f4(*(const ushort4*)&sW[(k + 2) * D_ + jc]);
            float4 b3 = b2f4(*(const ushort4*)&sW[(k + 3) * D_ + jc]);
            FMA4(a0.x, b0, acc0) FMA4(a0.y, b1, acc0) FMA4(a0.z, b2, acc0) FMA4(a0.w, b3, acc0)
            FMA4(a1.x, b0, acc1) FMA4(a1.y, b1, acc1) FMA4(a1.z, b2, acc1) FMA4(a1.w, b3, acc1)
        }
        #define EPILOG(AC, ROFF) { \
            int row = r0 + rr + ROFF; \
            long pos = (long)row * 32 + (tid & 31); \
            float4 p = b2f4(xin4[pos]); \
            float4 o; \
            o.x = p.x + fmaxf(AC[0] + bv.x, 0.f); o.y = p.y + fmaxf(AC[1] + bv.y, 0.f); \
            o.z = p.z + fmaxf(AC[2] + bv.z, 0.f); o.w = p.w + fmaxf(AC[3] + bv.w, 0.f); \
            xout4[pos] = f2b4(o); }
        EPILOG(acc0, 0)
        EPILOG(acc1, 1)
        #undef EPILOG
    }
}

// ---------------- patch feature assembly (in place): s = s/cnt + patch_pe @ prw_W + prw_b ----------------
__global__ void k_sx(float* __restrict__ s, const int* __restrict__ pcnt,
                     const float* __restrict__ ppe, const float* __restrict__ pW,
                     const float* __restrict__ pb){
    int i = blockIdx.x * 256 + threadIdx.x;
    if (i >= BP_ * D_) return;
    int r = i >> 7, d = i & 127;
    float acc = s[i] / fmaxf((float)pcnt[r], 1.0f) + pb[d];
    #pragma unroll
    for (int k = 0; k < PRW_; k++) acc = fmaf(ppe[r * PRW_ + k], pW[k * D_ + d], acc);
    s[i] = acc;
}

// ---------------- mixer: token mixing (one block per graph) ----------------
__global__ __launch_bounds__(256)
void k_token_mix(float* __restrict__ m, const float* __restrict__ g, const float* __restrict__ be,
                 const float* __restrict__ tW1, const float* __restrict__ tb1,
                 const float* __restrict__ tW2, const float* __restrict__ tb2){
    __shared__ float sy[P_][D_];        // 16 KB
    __shared__ float sh[D_][TH_ + 1];   // 33.3 KB (total 49.3 KB)
    int b = blockIdx.x, tid = threadIdx.x;
    float* mb = m + (long)b * P_ * D_;
    int wv = tid >> 6, ln_ = tid & 63;
    for (int r = wv; r < P_; r += 4){
        float v0 = mb[r * D_ + ln_], v1 = mb[r * D_ + 64 + ln_];
        float s = v0 + v1, ss = v0 * v0 + v1 * v1;
        #pragma unroll
        for (int o = 32; o > 0; o >>= 1){ s += __shfl_down(s, o, 64); ss += __shfl_down(ss, o, 64); }
        s = __shfl(s, 0, 64); ss = __shfl(ss, 0, 64);
        float mu = s * (1.f / 128.f);
        float var = ss * (1.f / 128.f) - mu * mu;
        float rs = rsqrtf(var + 1e-5f);
        sy[r][ln_]      = (v0 - mu) * rs * g[ln_]      + be[ln_];
        sy[r][64 + ln_] = (v1 - mu) * rs * g[64 + ln_] + be[64 + ln_];
    }
    __syncthreads();
    for (int o = tid; o < D_ * TH_; o += 256){
        int t = o & 63, d = o >> 6;
        float a = tb1[t];
        #pragma unroll
        for (int p = 0; p < P_; p++) a = fmaf(sy[p][d], tW1[p * TH_ + t], a);
        sh[d][t] = gelu_t(a);
    }
    __syncthreads();
    for (int o = tid; o < P_ * D_; o += 256){
        int d = o & 127, p = o >> 7;
        float a = tb2[p];
        #pragma unroll
        for (int t = 0; t < TH_; t++) a = fmaf(sh[d][t], tW2[t * P_ + p], a);
        mb[p * D_ + d] += a;
    }
}

// ---------------- mixer: channel mixing (16 rows per block) ----------------
__global__ __launch_bounds__(256)
void k_channel_mix(float* __restrict__ m, const float* __restrict__ g, const float* __restrict__ be,
                   const float* __restrict__ cW1, const float* __restrict__ cb1,
                   const float* __restrict__ cW2, const float* __restrict__ cb2){
    __shared__ float sy[16][D_];        // 8 KB
    __shared__ float sh[16][CH_ + 1];   // 32.8 KB (total 40.8 KB)
    int r0 = blockIdx.x * 16, tid = threadIdx.x;
    int wv = tid >> 6, ln_ = tid & 63;
    for (int r = wv; r < 16; r += 4){
        float v0 = m[(long)(r0 + r) * D_ + ln_], v1 = m[(long)(r0 + r) * D_ + 64 + ln_];
        float s = v0 + v1, ss = v0 * v0 + v1 * v1;
        #pragma unroll
        for (int o = 32; o > 0; o >>= 1){ s += __shfl_down(s, o, 64); ss += __shfl_down(ss, o, 64); }
        s = __shfl(s, 0, 64); ss = __shfl(ss, 0, 64);
        float mu = s * (1.f / 128.f);
        float var = ss * (1.f / 128.f) - mu * mu;
        float rs = rsqrtf(var + 1e-5f);
        sy[r][ln_]      = (v0 - mu) * rs * g[ln_]      + be[ln_];
        sy[r][64 + ln_] = (v1 - mu) * rs * g[64 + ln_] + be[64 + ln_];
    }
    __syncthreads();
    #pragma unroll
    for (int th = 0; th < 2; th++){
        int t = tid + th * 256;
        float acc[16];
        #pragma unroll
        for (int r = 0; r < 16; r++) acc[r] = cb1[t];
        for (int k = 0; k < D_; k++){
            float w = cW1[k * CH_ + t];
            #pragma unroll
            for (int r = 0; r < 16; r++) acc[r] = fmaf(sy[r][k], w, acc[r]);
        }
        #pragma unroll
        for (int r = 0; r < 16; r++) sh[r][t] = gelu_t(acc[r]);
    }
    __syncthreads();
    {
        int d = tid & 127, rbase = tid >> 7;
        float acc[8];
        #pragma unroll
        for (int q = 0; q < 8; q++) acc[q] = 0.f;
        for (int t = 0; t < CH_; t++){
            float w = cW2[t * D_ + d];
            #pragma unroll
            for (int q = 0; q < 8; q++) acc[q] = fmaf(sh[rbase + 2 * q][t], w, acc[q]);
        }
        float cb = cb2[d];
        #pragma unroll
        for (int q = 0; q < 8; q++){
            int row = r0 + rbase + 2 * q;
            m[(long)row * D_ + d] += acc[q] + cb;
        }
    }
}

// ---------------- final pooled head ----------------
__global__ __launch_bounds__(128)
void k_final(const float* __restrict__ m, const float* __restrict__ oW1, const float* __restrict__ ob1,
             const float* __restrict__ oW2, const float* __restrict__ ob2, float* __restrict__ out){
    __shared__ float sp[D_];
    __shared__ float red[128];
    int b = blockIdx.x, tid = threadIdx.x;
    float a = 0.f;
    for (int p = 0; p < P_; p++) a += m[(long)b * P_ * D_ + p * D_ + tid];
    sp[tid] = a * (1.0f / P_);
    __syncthreads();
    float h = ob1[tid];
    for (int d = 0; d < D_; d++) h = fmaf(sp[d], oW1[d * D_ + tid], h);
    h = fmaxf(h, 0.f) * oW2[tid];
    red[tid] = h;
    __syncthreads();
    for (int s = 64; s > 0; s >>= 1){
        if (tid < s) red[tid] += red[tid + s];
        __syncthreads();
    }
    if (tid == 0) out[b] = red[0] + ob2[0];
}

extern "C" void kernel_launch(void* const* d_in, const int* in_sizes, int n_in,
                              void* d_out, int out_size, void* d_ws, size_t ws_size,
                              hipStream_t stream){
    const int*   x_atom       = (const int*)  d_in[0];
    const float* rw_pe        = (const float*)d_in[1];
    const int*   edge_attr    = (const int*)  d_in[2];
    const int*   nodes_mapper = (const int*)  d_in[3];
    const int*   edges_mapper = (const int*)  d_in[4];
    const int*   edge_index   = (const int*)  d_in[5];
    const int*   batch_x      = (const int*)  d_in[6];
    const float* patch_pe     = (const float*)d_in[7];
    // d_in[8] = mask, all-true by construction -> mean pooling
    const float* atom_emb = (const float*)d_in[9];
    const float* bond_emb = (const float*)d_in[10];
    const float* rw_W  = (const float*)d_in[11];
    const float* rw_b  = (const float*)d_in[12];
    const float* prw_W = (const float*)d_in[13];
    const float* prw_b = (const float*)d_in[14];
    const float* gnn_W = (const float*)d_in[15];
    const float* gnn_b = (const float*)d_in[16];
    const float* U_W   = (const float*)d_in[17];
    const float* U_b   = (const float*)d_in[18];
    const float* ln1_g = (const float*)d_in[19];
    const float* ln1_b = (const float*)d_in[20];
    const float* tW1   = (const float*)d_in[21];
    const float* tb1   = (const float*)d_in[22];
    const float* tW2   = (const float*)d_in[23];
    const float* tb2   = (const float*)d_in[24];
    const float* ln2_g = (const float*)d_in[25];
    const float* ln2_b = (const float*)d_in[26];
    const float* cW1   = (const float*)d_in[27];
    const float* cb1   = (const float*)d_in[28];
    const float* cW2   = (const float*)d_in[29];
    const float* cb2   = (const float*)d_in[30];
    const float* oW1   = (const float*)d_in[31];
    const float* ob1   = (const float*)d_in[32];
    const float* oW2   = (const float*)d_in[33];
    const float* ob2   = (const float*)d_in[34];

    const int* srcv = edge_index;
    const int* dstv = edge_index + ES_;

    // ---- workspace layout: 267,029,248 B <= 256 MiB ----
    char* w = (char*)d_ws;
    const size_t SZ_PONG = (size_t)NS_ * D_ * 2;     // 128,000,000
    size_t offA    = 0;
    size_t offB    = SZ_PONG;                                 // 128,000,000
    size_t offSUB  = offB    + SZ_PONG;                       // 256,000,000 (4,194,304: cursor/sub/mbuf)
    size_t offRP   = offSUB  + (size_t)BP_ * D_ * 4;          // 260,194,304 (2,000,128)
    size_t offEP   = offRP   + 2000128;                       // 262,194,432 (4,000,000)
    size_t offPC   = offEP   + (size_t)ES_ * 4;               // 266,194,432
    size_t offNC   = offPC   + (size_t)BP_ * 4;               // 266,227,200
    size_t offBS   = offNC   + (size_t)N_ORIG * 4;            // 267,027,200
    size_t needed  = offBS   + 512 * 4;                       // 267,029,248

    if (ws_size < needed){
        k_breadcrumb<<<cdiv_l(out_size, 256), 256, 0, stream>>>((float*)d_out, out_size,
                                                                (float)(ws_size >> 20));
        return;
    }

    ushort_t* bufA = (ushort_t*)(w + offA);
    ushort_t* bufB = (ushort_t*)(w + offB);
    float*    sub  = (float*)(w + offSUB);     // also: cursor (CSR build), mixer mbuf
    int*      rp   = (int*)(w + offRP);
    int*      ep   = (int*)(w + offEP);
    int*      pcnt = (int*)(w + offPC);
    int*      ncnt = (int*)(w + offNC);
    int*      bsum = (int*)(w + offBS);
    int*      cursor = (int*)sub;

    const int TPB = 256;
    int gNSrow = cdiv_l((long)NS_ * 32, TPB);
    int gBProw = cdiv_l((long)BP_ * 32, TPB);
    int nScanB = cdiv_l(NS_, 1024);            // 489

    // ---- CSR build + counts ----
    hipMemsetAsync(rp, 0, (size_t)(NS_ + 1) * 4, stream);
    hipMemsetAsync(pcnt, 0, (size_t)BP_ * 4, stream);
    hipMemsetAsync(ncnt, 0, (size_t)N_ORIG * 4, stream);
    k_counts<<<cdiv_l(NS_, TPB), TPB, 0, stream>>>(batch_x, nodes_mapper, pcnt, ncnt);
    k_deg<<<cdiv_l(ES_, TPB), TPB, 0, stream>>>(dstv, rp);
    k_scan1<<<nScanB, TPB, 0, stream>>>(rp, bsum);
    k_scan2<<<1, 512, 0, stream>>>(bsum, nScanB);
    k_scan3<<<cdiv_l(NS_ + 1, TPB), TPB, 0, stream>>>(rp, bsum, cursor);
    k_scatter<<<cdiv_l(ES_, TPB), TPB, 0, stream>>>(srcv, dstv, edge_attr, edges_mapper, cursor, ep);

    // ---- encode ----
    float* x0 = (float*)bufA;
    k_encode<<<cdiv_l((long)N_ORIG * D_, TPB), TPB, 0, stream>>>(x_atom, rw_pe, atom_emb, rw_W, rw_b, x0);
    k_gather_f2b<<<gNSrow, TPB, 0, stream>>>((const float4*)x0, nodes_mapper, (ushort4*)bufB, NS_);

    ushort_t* cur = bufB;
    ushort_t* oth = bufA;

    for (int i = 0; i < 4; i++){
        if (i > 0){
            hipMemsetAsync(sub, 0, (size_t)BP_ * D_ * 4, stream);
            k_seg_add_b<<<gNSrow, TPB, 0, stream>>>((const ushort4*)cur, batch_x, sub, NS_);
            k_div_cnt4<<<gBProw, TPB, 0, stream>>>((float4*)sub, pcnt, BP_);
            ushort_t* subT = (ushort_t*)((char*)oth + 104857600);  // inside dead pong buffer
            k_gemm128<<<512, TPB, 0, stream>>>(sub, U_W + (i - 1) * D_ * D_,
                                               U_b + (i - 1) * D_, subT, BP_);
            k_gather_add_b<<<gNSrow, TPB, 0, stream>>>((ushort4*)cur, (const ushort4*)subT, batch_x, NS_);
            float* nsum = (float*)oth;
            hipMemsetAsync(nsum, 0, (size_t)N_ORIG * D_ * 4, stream);
            k_seg_add_b<<<gNSrow, TPB, 0, stream>>>((const ushort4*)cur, nodes_mapper, nsum, NS_);
            k_gather_div_b<<<gNSrow, TPB, 0, stream>>>((ushort4*)cur, (const float4*)nsum, ncnt, nodes_mapper, NS_);
        }
        k_gemm_conv<<<2048, TPB, 0, stream>>>(cur, oth, rp, ep, bond_emb,
                                              gnn_W + i * D_ * D_, gnn_b + i * D_);
        ushort_t* t = cur; cur = oth; oth = t;
    }

    // ---- patch pooling + mixer (sub doubles as m buffer, in place) ----
    hipMemsetAsync(sub, 0, (size_t)BP_ * D_ * 4, stream);
    k_seg_add_b<<<gNSrow, TPB, 0, stream>>>((const ushort4*)cur, batch_x, sub, NS_);
    k_sx<<<cdiv_l((long)BP_ * D_, TPB), TPB, 0, stream>>>(sub, pcnt, patch_pe, prw_W, prw_b);

    for (int l = 0; l < 2; l++){
        k_token_mix<<<B_, TPB, 0, stream>>>(sub, ln1_g + l * D_, ln1_b + l * D_,
                                            tW1 + l * P_ * TH_, tb1 + l * TH_,
                                            tW2 + l * TH_ * P_, tb2 + l * P_);
        k_channel_mix<<<BP_ / 16, TPB, 0, stream>>>(sub, ln2_g + l * D_, ln2_b + l * D_,
                                                    cW1 + l * D_ * CH_, cb1 + l * CH_,
                                                    cW2 + l * CH_ * D_, cb2 + l * D_);
    }
    k_final<<<B_, 128, 0, stream>>>(sub, oW1, ob1, oW2, ob2, (float*)d_out);
}

// Round 5
// 2315.770 us; speedup vs baseline: 3.8350x; 3.8350x over previous
//
#include <hip/hip_runtime.h>
#include <hip/hip_bf16.h>
#include <math.h>

#define N_ORIG 200000
#define NS_    500000
#define ES_    1000000
#define B_     256
#define P_     32
#define D_     128
#define BP_    8192
#define RW_    20
#define PRW_   8
#define TH_    64
#define CH_    512

static inline int cdiv_l(long a, long b){ return (int)((a + b - 1) / b); }

typedef unsigned short ushort_t;
typedef __attribute__((ext_vector_type(8))) short gmx_bv8;   // 8 bf16 (4 VGPRs)
typedef __attribute__((ext_vector_type(4))) float gmx_fv4;   // 4 f32 acc

__device__ __forceinline__ float b2f(ushort_t u){
    union { unsigned int i; float f; } c; c.i = ((unsigned int)u) << 16; return c.f;
}
__device__ __forceinline__ ushort_t f2b(float f){
    union { float f; unsigned int u; } c; c.f = f;
    unsigned int u = c.u;
    u += 0x7fffu + ((u >> 16) & 1u);      // RNE
    return (ushort_t)(u >> 16);
}
__device__ __forceinline__ float4 b2f4(ushort4 v){
    return make_float4(b2f(v.x), b2f(v.y), b2f(v.z), b2f(v.w));
}
__device__ __forceinline__ ushort4 f2b4(float4 v){
    ushort4 r; r.x = f2b(v.x); r.y = f2b(v.y); r.z = f2b(v.z); r.w = f2b(v.w); return r;
}

__device__ __forceinline__ float gelu_t(float x){
    float t = tanhf(0.7978845608028654f * (x + 0.044715f * x * x * x));
    return 0.5f * x * (1.0f + t);
}

// ---------------- diagnostics ----------------
__global__ void k_breadcrumb(float* __restrict__ out, int n, float v){
    int i = blockIdx.x * 256 + threadIdx.x;
    if (i < n) out[i] = v;
}

// ---------------- degree histograms ----------------
__global__ void k_deg_edges(const int* __restrict__ dstv, int* __restrict__ deg){
    int e = blockIdx.x * 256 + threadIdx.x;
    if (e >= ES_) return;
    atomicAdd(&deg[dstv[e]], 1);
}

__global__ void k_deg_ns(const int* __restrict__ bx, const int* __restrict__ nm,
                         int* __restrict__ pdeg, int* __restrict__ ndeg){
    int i = blockIdx.x * 256 + threadIdx.x;
    if (i >= NS_) return;
    atomicAdd(&pdeg[bx[i]], 1);
    atomicAdd(&ndeg[nm[i]], 1);
}

// ---------------- generic 3-phase exclusive scan (n <= 512*1024) ----------------
__global__ __launch_bounds__(256)
void k_scan1(int* __restrict__ a, int* __restrict__ bsum, int n){
    __shared__ int sb[256];
    int tid = threadIdx.x;
    long base = (long)blockIdx.x * 1024 + tid * 4;
    int v0 = 0, v1 = 0, v2 = 0, v3 = 0;
    if (base + 0 < n) v0 = a[base + 0];
    if (base + 1 < n) v1 = a[base + 1];
    if (base + 2 < n) v2 = a[base + 2];
    if (base + 3 < n) v3 = a[base + 3];
    int tsum = v0 + v1 + v2 + v3;
    sb[tid] = tsum;
    __syncthreads();
    for (int o = 1; o < 256; o <<= 1){
        int t = (tid >= o) ? sb[tid - o] : 0;
        __syncthreads();
        sb[tid] += t;
        __syncthreads();
    }
    int excl = sb[tid] - tsum;
    if (tid == 255) bsum[blockIdx.x] = sb[255];
    if (base + 0 < n) a[base + 0] = excl;
    if (base + 1 < n) a[base + 1] = excl + v0;
    if (base + 2 < n) a[base + 2] = excl + v0 + v1;
    if (base + 3 < n) a[base + 3] = excl + v0 + v1 + v2;
}

__global__ __launch_bounds__(512)
void k_scan2(int* __restrict__ bsum, int nb){
    __shared__ int sb[512];
    int tid = threadIdx.x;
    int orig = (tid < nb) ? bsum[tid] : 0;
    sb[tid] = orig;
    __syncthreads();
    for (int o = 1; o < 512; o <<= 1){
        int t = (tid >= o) ? sb[tid - o] : 0;
        __syncthreads();
        sb[tid] += t;
        __syncthreads();
    }
    if (tid < nb) bsum[tid] = sb[tid] - orig;
}

__global__ void k_scan3(int* __restrict__ a, const int* __restrict__ bsum,
                        int* __restrict__ cursor, int n, int total){
    long i = (long)blockIdx.x * 256 + threadIdx.x;
    if (i < n){
        int v = a[i] + bsum[i >> 10];
        a[i] = v;
        cursor[i] = v;
    } else if (i == n){
        a[n] = total;
    }
}

// ---------------- CSR scatters ----------------
__global__ void k_scatter_edges(const int* __restrict__ srcv, const int* __restrict__ dstv,
                                const int* __restrict__ ea, const int* __restrict__ em,
                                int* __restrict__ cursor, int* __restrict__ epack){
    int e = blockIdx.x * 256 + threadIdx.x;
    if (e >= ES_) return;
    int pos = atomicAdd(&cursor[dstv[e]], 1);
    epack[pos] = srcv[e] | (ea[em[e]] << 20);
}

__global__ void k_scatter_ns(const int* __restrict__ bx, const int* __restrict__ nm,
                             int* __restrict__ cur_p, int* __restrict__ cur_n,
                             int* __restrict__ plist, int* __restrict__ nlist){
    int i = blockIdx.x * 256 + threadIdx.x;
    if (i >= NS_) return;
    int pp = atomicAdd(&cur_p[bx[i]], 1);
    plist[pp] = i;
    int pn = atomicAdd(&cur_n[nm[i]], 1);
    nlist[pn] = i;
}

// ---------------- fused encode + gather: xs[i] = enc(nodes_mapper[i]) ----------------
__global__ void k_encode_gather(const int* __restrict__ xa, const float* __restrict__ rw,
                                const int* __restrict__ nm, const float* __restrict__ aemb,
                                const float* __restrict__ rwW, const float* __restrict__ rwb,
                                ushort_t* __restrict__ xs){
    long i = (long)blockIdx.x * 256 + threadIdx.x;
    if (i >= (long)NS_ * 32) return;
    int r = (int)(i >> 5), q = (int)(i & 31);
    int n = nm[r];
    const float4* aemb4 = (const float4*)aemb;
    const float4* rwW4  = (const float4*)rwW;
    const float4* rwb4  = (const float4*)rwb;
    float4 v = aemb4[(long)xa[n] * 32 + q];
    float4 bb = rwb4[q];
    v.x += bb.x; v.y += bb.y; v.z += bb.z; v.w += bb.w;
    const float* rr = rw + (long)n * RW_;
    #pragma unroll
    for (int k = 0; k < RW_; k++){
        float rv = rr[k];
        float4 ww = rwW4[k * 32 + q];
        v.x = fmaf(rv, ww.x, v.x); v.y = fmaf(rv, ww.y, v.y);
        v.z = fmaf(rv, ww.z, v.z); v.w = fmaf(rv, ww.w, v.w);
    }
    ((ushort4*)xs)[i] = f2b4(v);
}

// ---------------- patch pooling via CSR (bf16 mean, pre-step) ----------------
__global__ __launch_bounds__(128)
void k_patch_pool(const ushort_t* __restrict__ xs, const int* __restrict__ prp,
                  const int* __restrict__ plist, ushort_t* __restrict__ pm){
    int p = blockIdx.x, d = threadIdx.x;
    int j0 = prp[p], j1 = prp[p + 1];
    float s = 0.f;
    for (int j = j0; j < j1; j++) s += b2f(xs[(long)plist[j] * D_ + d]);
    pm[(long)p * D_ + d] = f2b(s / fmaxf((float)(j1 - j0), 1.f));
}

// ---------------- final patch pooling + PE (f32 out) ----------------
__global__ __launch_bounds__(128)
void k_patch_pool_sx(const ushort_t* __restrict__ xs, const int* __restrict__ prp,
                     const int* __restrict__ plist, const float* __restrict__ ppe,
                     const float* __restrict__ pW, const float* __restrict__ pb,
                     float* __restrict__ m){
    int p = blockIdx.x, d = threadIdx.x;
    int j0 = prp[p], j1 = prp[p + 1];
    float s = 0.f;
    for (int j = j0; j < j1; j++) s += b2f(xs[(long)plist[j] * D_ + d]);
    s = s / fmaxf((float)(j1 - j0), 1.f) + pb[d];
    #pragma unroll
    for (int k = 0; k < PRW_; k++) s = fmaf(ppe[p * PRW_ + k], pW[k * D_ + d], s);
    m[(long)p * D_ + d] = s;
}

// ---------------- node sync via CSR: all copies of node n <- mean(copies) ----------------
__global__ __launch_bounds__(128)
void k_node_sync(ushort_t* __restrict__ xs, const int* __restrict__ nrp,
                 const int* __restrict__ nlist){
    int n = blockIdx.x, d = threadIdx.x;
    int j0 = nrp[n], j1 = nrp[n + 1];
    if (j0 >= j1) return;
    float s = 0.f;
    for (int j = j0; j < j1; j++) s += b2f(xs[(long)nlist[j] * D_ + d]);
    ushort_t v = f2b(s / (float)(j1 - j0));
    for (int j = j0; j < j1; j++) xs[(long)nlist[j] * D_ + d] = v;
}

// ---------------- xs += rows[map] (bf16) ----------------
__global__ void k_gather_add_b(ushort4* __restrict__ x, const ushort4* __restrict__ rows,
                               const int* __restrict__ map, int n){
    int i = blockIdx.x * 256 + threadIdx.x;
    if (i >= n * 32) return;
    float4 v = b2f4(x[i]);
    float4 u = b2f4(rows[(long)map[i >> 5] * 32 + (i & 31)]);
    v.x += u.x; v.y += u.y; v.z += u.z; v.w += u.w;
    x[i] = f2b4(v);
}

// ---------------- U-step GEMM: out_bf16 = relu(in_bf16 @ W + b) ----------------
#define FMA4(AV, BV, AC) { AC[0]=fmaf(AV,BV.x,AC[0]); AC[1]=fmaf(AV,BV.y,AC[1]); AC[2]=fmaf(AV,BV.z,AC[2]); AC[3]=fmaf(AV,BV.w,AC[3]); }

__global__ __launch_bounds__(256)
void k_gemm128(const ushort_t* __restrict__ in1, const float* __restrict__ W,
               const float* __restrict__ bvec, ushort_t* __restrict__ out, int nrows){
    __shared__ ushort_t sW[D_ * D_];    // 32 KB
    __shared__ float sIn[16 * 132];     // 8.25 KB
    int tid = threadIdx.x;
    for (int k = tid; k < D_ * D_; k += 256) sW[k] = f2b(W[k]);
    int jc = (tid & 31) * 4;
    int rr = (tid >> 5) * 2;
    float4 bv = *(const float4*)&bvec[jc];
    const ushort4* in1_4 = (const ushort4*)in1;
    ushort4* out_4 = (ushort4*)out;
    int ntiles = (nrows + 15) / 16;
    for (int tile = blockIdx.x; tile < ntiles; tile += gridDim.x){
        int r0 = tile * 16;
        __syncthreads();
        for (int k = tid; k < 16 * 32; k += 256){
            int r = k >> 5, q = k & 31;
            float4 v = make_float4(0.f, 0.f, 0.f, 0.f);
            if (r0 + r < nrows) v = b2f4(in1_4[(long)(r0 + r) * 32 + q]);
            *(float4*)&sIn[r * 132 + q * 4] = v;
        }
        __syncthreads();
        float acc0[4] = {0.f,0.f,0.f,0.f}, acc1[4] = {0.f,0.f,0.f,0.f};
        for (int k = 0; k < D_; k += 4){
            float4 a0 = *(const float4*)&sIn[(rr + 0) * 132 + k];
            float4 a1 = *(const float4*)&sIn[(rr + 1) * 132 + k];
            float4 b0 = b2f4(*(const ushort4*)&sW[(k + 0) * D_ + jc]);
            float4 b1 = b2f4(*(const ushort4*)&sW[(k + 1) * D_ + jc]);
            float4 b2 = b2f4(*(const ushort4*)&sW[(k + 2) * D_ + jc]);
            float4 b3 = b2f4(*(const ushort4*)&sW[(k + 3) * D_ + jc]);
            FMA4(a0.x, b0, acc0) FMA4(a0.y, b1, acc0) FMA4(a0.z, b2, acc0) FMA4(a0.w, b3, acc0)
            FMA4(a1.x, b0, acc1) FMA4(a1.y, b1, acc1) FMA4(a1.z, b2, acc1) FMA4(a1.w, b3, acc1)
        }
        #define EPILOG(AC, ROFF) { \
            int row = r0 + rr + ROFF; \
            if (row < nrows){ \
                float4 o; \
                o.x = fmaxf(AC[0] + bv.x, 0.f); o.y = fmaxf(AC[1] + bv.y, 0.f); \
                o.z = fmaxf(AC[2] + bv.z, 0.f); o.w = fmaxf(AC[3] + bv.w, 0.f); \
                out_4[(long)row * 32 + (tid & 31)] = f2b4(o); \
            } }
        EPILOG(acc0, 0)
        EPILOG(acc1, 1)
        #undef EPILOG
    }
}

// ---------------- MFMA conv: xout = xin + relu((xin + agg_csr) @ W + b) ----------------
// 16-row tiles; A staged bf16 in swizzled LDS; W pre-fragmented bf16 in LDS.
#define CROWS 16

__global__ __launch_bounds__(256)
void k_conv_mfma(const ushort_t* __restrict__ xin, ushort_t* __restrict__ xout,
                 const int* __restrict__ rp, const int* __restrict__ epack,
                 const float* __restrict__ bond, const float* __restrict__ W,
                 const float* __restrict__ bvec){
    __shared__ ushort_t sWf[D_ * D_];     // 32 KB fragment-ordered bf16 weights
    __shared__ char sInB[CROWS * 256];    // 4 KB bf16 A-tile (swizzled rows)
    int tid = threadIdx.x;
    // Fill weight fragments: unit u = (nb*4 + kb)*64 + l, nb=0..7, kb=0..3, l=0..63.
    // Lane l of tile (nb,kb) holds W[kb*32 + 8*(l>>4) + j][nb*16 + (l&15)], j=0..7.
    for (int u = tid; u < 2048; u += 256){
        int l = u & 63, t2 = u >> 6;
        int kb = t2 & 3, nb = t2 >> 2;
        int col = nb * 16 + (l & 15);
        int kr  = kb * 32 + 8 * (l >> 4);
        ushort4 lo, hi;
        lo.x = f2b(W[(kr + 0) * D_ + col]); lo.y = f2b(W[(kr + 1) * D_ + col]);
        lo.z = f2b(W[(kr + 2) * D_ + col]); lo.w = f2b(W[(kr + 3) * D_ + col]);
        hi.x = f2b(W[(kr + 4) * D_ + col]); hi.y = f2b(W[(kr + 5) * D_ + col]);
        hi.z = f2b(W[(kr + 6) * D_ + col]); hi.w = f2b(W[(kr + 7) * D_ + col]);
        *(ushort4*)&sWf[u * 8 + 0] = lo;
        *(ushort4*)&sWf[u * 8 + 4] = hi;
    }
    int wid = tid >> 6, lane = tid & 63;
    int colA = lane & 15, rgrp = lane >> 4;
    int c0 = 32 * wid + colA, c1 = c0 + 16;    // this wave's two 16-col tiles
    float bias0 = bvec[c0], bias1 = bvec[c1];
    const ushort4* xin4 = (const ushort4*)xin;
    const float4* bond4 = (const float4*)bond;
    const int ntiles = NS_ / CROWS;
    __syncthreads();
    for (int tile = blockIdx.x; tile < ntiles; tile += gridDim.x){
        int r0 = tile * CROWS;
        // ---- stage A = x + sum relu(x_src + e) ----
        #pragma unroll
        for (int it = 0; it < 2; it++){
            int k = tid + it * 256;
            int r = k >> 5, q = k & 31;
            int row = r0 + r;
            float4 v = b2f4(xin4[(long)row * 32 + q]);
            int e0 = rp[row], e1 = rp[row + 1];
            for (int e = e0; e < e1; e++){
                int pk = epack[e];
                float4 u = b2f4(xin4[(long)(pk & 0xFFFFF) * 32 + q]);
                float4 bb = bond4[(pk >> 20) * 32 + q];
                v.x += fmaxf(u.x + bb.x, 0.f);
                v.y += fmaxf(u.y + bb.y, 0.f);
                v.z += fmaxf(u.z + bb.z, 0.f);
                v.w += fmaxf(u.w + bb.w, 0.f);
            }
            int off = (r * 256 + q * 8) ^ ((r & 7) << 4);
            *(ushort4*)&sInB[off] = f2b4(v);
        }
        __syncthreads();
        // ---- MFMA: D[16 rows x 32 cols] per wave ----
        gmx_fv4 acc0 = {0.f,0.f,0.f,0.f}, acc1 = {0.f,0.f,0.f,0.f};
        #pragma unroll
        for (int kb = 0; kb < 4; kb++){
            int kslot = kb * 4 + rgrp;
            gmx_bv8 a = *(const gmx_bv8*)&sInB[(colA * 256 + kslot * 16) ^ ((colA & 7) << 4)];
            gmx_bv8 b0 = *(const gmx_bv8*)&sWf[(((2 * wid + 0) * 4 + kb) * 64 + lane) * 8];
            gmx_bv8 b1 = *(const gmx_bv8*)&sWf[(((2 * wid + 1) * 4 + kb) * 64 + lane) * 8];
            acc0 = __builtin_amdgcn_mfma_f32_16x16x32_bf16(a, b0, acc0, 0, 0, 0);
            acc1 = __builtin_amdgcn_mfma_f32_16x16x32_bf16(a, b1, acc1, 0, 0, 0);
        }
        // ---- epilogue: D row = rgrp*4 + ri, col = c0/c1 ----
        #pragma unroll
        for (int ri = 0; ri < 4; ri++){
            long base = (long)(r0 + rgrp * 4 + ri) * D_;
            float o0 = b2f(xin[base + c0]) + fmaxf(acc0[ri] + bias0, 0.f);
            float o1 = b2f(xin[base + c1]) + fmaxf(acc1[ri] + bias1, 0.f);
            xout[base + c0] = f2b(o0);
            xout[base + c1] = f2b(o1);
        }
        __syncthreads();
    }
}

// ---------------- mixer: token mixing (one block per graph) ----------------
__global__ __launch_bounds__(256)
void k_token_mix(float* __restrict__ m, const float* __restrict__ g, const float* __restrict__ be,
                 const float* __restrict__ tW1, const float* __restrict__ tb1,
                 const float* __restrict__ tW2, const float* __restrict__ tb2){
    __shared__ float sy[P_][D_];        // 16 KB
    __shared__ float sh[D_][TH_ + 1];   // 33.3 KB
    int b = blockIdx.x, tid = threadIdx.x;
    float* mb = m + (long)b * P_ * D_;
    int wv = tid >> 6, ln_ = tid & 63;
    for (int r = wv; r < P_; r += 4){
        float v0 = mb[r * D_ + ln_], v1 = mb[r * D_ + 64 + ln_];
        float s = v0 + v1, ss = v0 * v0 + v1 * v1;
        #pragma unroll
        for (int o = 32; o > 0; o >>= 1){ s += __shfl_down(s, o, 64); ss += __shfl_down(ss, o, 64); }
        s = __shfl(s, 0, 64); ss = __shfl(ss, 0, 64);
        float mu = s * (1.f / 128.f);
        float var = ss * (1.f / 128.f) - mu * mu;
        float rs = rsqrtf(var + 1e-5f);
        sy[r][ln_]      = (v0 - mu) * rs * g[ln_]      + be[ln_];
        sy[r][64 + ln_] = (v1 - mu) * rs * g[64 + ln_] + be[64 + ln_];
    }
    __syncthreads();
    for (int o = tid; o < D_ * TH_; o += 256){
        int t = o & 63, d = o >> 6;
        float a = tb1[t];
        #pragma unroll
        for (int p = 0; p < P_; p++) a = fmaf(sy[p][d], tW1[p * TH_ + t], a);
        sh[d][t] = gelu_t(a);
    }
    __syncthreads();
    for (int o = tid; o < P_ * D_; o += 256){
        int d = o & 127, p = o >> 7;
        float a = tb2[p];
        #pragma unroll
        for (int t = 0; t < TH_; t++) a = fmaf(sh[d][t], tW2[t * P_ + p], a);
        mb[p * D_ + d] += a;
    }
}

// ---------------- mixer: channel mixing (16 rows per block) ----------------
__global__ __launch_bounds__(256)
void k_channel_mix(float* __restrict__ m, const float* __restrict__ g, const float* __restrict__ be,
                   const float* __restrict__ cW1, const float* __restrict__ cb1,
                   const float* __restrict__ cW2, const float* __restrict__ cb2){
    __shared__ float sy[16][D_];        // 8 KB
    __shared__ float sh[16][CH_ + 1];   // 32.8 KB
    int r0 = blockIdx.x * 16, tid = threadIdx.x;
    int wv = tid >> 6, ln_ = tid & 63;
    for (int r = wv; r < 16; r += 4){
        float v0 = m[(long)(r0 + r) * D_ + ln_], v1 = m[(long)(r0 + r) * D_ + 64 + ln_];
        float s = v0 + v1, ss = v0 * v0 + v1 * v1;
        #pragma unroll
        for (int o = 32; o > 0; o >>= 1){ s += __shfl_down(s, o, 64); ss += __shfl_down(ss, o, 64); }
        s = __shfl(s, 0, 64); ss = __shfl(ss, 0, 64);
        float mu = s * (1.f / 128.f);
        float var = ss * (1.f / 128.f) - mu * mu;
        float rs = rsqrtf(var + 1e-5f);
        sy[r][ln_]      = (v0 - mu) * rs * g[ln_]      + be[ln_];
        sy[r][64 + ln_] = (v1 - mu) * rs * g[64 + ln_] + be[64 + ln_];
    }
    __syncthreads();
    #pragma unroll
    for (int th = 0; th < 2; th++){
        int t = tid + th * 256;
        float acc[16];
        #pragma unroll
        for (int r = 0; r < 16; r++) acc[r] = cb1[t];
        for (int k = 0; k < D_; k++){
            float w = cW1[k * CH_ + t];
            #pragma unroll
            for (int r = 0; r < 16; r++) acc[r] = fmaf(sy[r][k], w, acc[r]);
        }
        #pragma unroll
        for (int r = 0; r < 16; r++) sh[r][t] = gelu_t(acc[r]);
    }
    __syncthreads();
    {
        int d = tid & 127, rbase = tid >> 7;
        float acc[8];
        #pragma unroll
        for (int q = 0; q < 8; q++) acc[q] = 0.f;
        for (int t = 0; t < CH_; t++){
            float w = cW2[t * D_ + d];
            #pragma unroll
            for (int q = 0; q < 8; q++) acc[q] = fmaf(sh[rbase + 2 * q][t], w, acc[q]);
        }
        float cb = cb2[d];
        #pragma unroll
        for (int q = 0; q < 8; q++){
            int row = r0 + rbase + 2 * q;
            m[(long)row * D_ + d] += acc[q] + cb;
        }
    }
}

// ---------------- final pooled head ----------------
__global__ __launch_bounds__(128)
void k_final(const float* __restrict__ m, const float* __restrict__ oW1, const float* __restrict__ ob1,
             const float* __restrict__ oW2, const float* __restrict__ ob2, float* __restrict__ out){
    __shared__ float sp[D_];
    __shared__ float red[128];
    int b = blockIdx.x, tid = threadIdx.x;
    float a = 0.f;
    for (int p = 0; p < P_; p++) a += m[(long)b * P_ * D_ + p * D_ + tid];
    sp[tid] = a * (1.0f / P_);
    __syncthreads();
    float h = ob1[tid];
    for (int d = 0; d < D_; d++) h = fmaf(sp[d], oW1[d * D_ + tid], h);
    h = fmaxf(h, 0.f) * oW2[tid];
    red[tid] = h;
    __syncthreads();
    for (int s = 64; s > 0; s >>= 1){
        if (tid < s) red[tid] += red[tid + s];
        __syncthreads();
    }
    if (tid == 0) out[b] = red[0] + ob2[0];
}

extern "C" void kernel_launch(void* const* d_in, const int* in_sizes, int n_in,
                              void* d_out, int out_size, void* d_ws, size_t ws_size,
                              hipStream_t stream){
    const int*   x_atom       = (const int*)  d_in[0];
    const float* rw_pe        = (const float*)d_in[1];
    const int*   edge_attr    = (const int*)  d_in[2];
    const int*   nodes_mapper = (const int*)  d_in[3];
    const int*   edges_mapper = (const int*)  d_in[4];
    const int*   edge_index   = (const int*)  d_in[5];
    const int*   batch_x      = (const int*)  d_in[6];
    const float* patch_pe     = (const float*)d_in[7];
    // d_in[8] = mask, all-true by construction -> mean pooling
    const float* atom_emb = (const float*)d_in[9];
    const float* bond_emb = (const float*)d_in[10];
    const float* rw_W  = (const float*)d_in[11];
    const float* rw_b  = (const float*)d_in[12];
    const float* prw_W = (const float*)d_in[13];
    const float* prw_b = (const float*)d_in[14];
    const float* gnn_W = (const float*)d_in[15];
    const float* gnn_b = (const float*)d_in[16];
    const float* U_W   = (const float*)d_in[17];
    const float* U_b   = (const float*)d_in[18];
    const float* ln1_g = (const float*)d_in[19];
    const float* ln1_b = (const float*)d_in[20];
    const float* tW1   = (const float*)d_in[21];
    const float* tb1   = (const float*)d_in[22];
    const float* tW2   = (const float*)d_in[23];
    const float* tb2   = (const float*)d_in[24];
    const float* ln2_g = (const float*)d_in[25];
    const float* ln2_b = (const float*)d_in[26];
    const float* cW1   = (const float*)d_in[27];
    const float* cb1   = (const float*)d_in[28];
    const float* cW2   = (const float*)d_in[29];
    const float* cb2   = (const float*)d_in[30];
    const float* oW1   = (const float*)d_in[31];
    const float* ob1   = (const float*)d_in[32];
    const float* oW2   = (const float*)d_in[33];
    const float* ob2   = (const float*)d_in[34];

    const int* srcv = edge_index;
    const int* dstv = edge_index + ES_;

    // ---- workspace layout: 266,835,008 B <= 256 MiB ----
    char* w = (char*)d_ws;
    const size_t SZ_PONG = (size_t)NS_ * D_ * 2;              // 128,000,000
    size_t offA   = 0;
    size_t offB   = SZ_PONG;                                  // 128,000,000
    size_t offRP  = offB   + SZ_PONG;                         // 256,000,000
    size_t offEP  = offRP  + 2000064;                         // edge rp (NS+1)*4 padded
    size_t offPRP = offEP  + (size_t)ES_ * 4;                 // patch rp (BP+1)*4
    size_t offPL  = offPRP + 32832;
    size_t offNRP = offPL  + (size_t)NS_ * 4;                 // node rp (N+1)*4
    size_t offNL  = offNRP + 800064;
    size_t offBS  = offNL  + (size_t)NS_ * 4;
    size_t needed = offBS  + 2048;                            // 266,835,008

    if (ws_size < needed){
        k_breadcrumb<<<cdiv_l(out_size, 256), 256, 0, stream>>>((float*)d_out, out_size,
                                                                (float)(ws_size >> 20));
        return;
    }

    // canary: if pipeline dies mid-way without raising, absmax ≈ 6.7 identifies it;
    // absmax ≈ 0.32 means even this never ran (build/module failure).
    k_breadcrumb<<<cdiv_l(out_size, 256), 256, 0, stream>>>((float*)d_out, out_size, 7.0f);

    ushort_t* bufA = (ushort_t*)(w + offA);
    ushort_t* bufB = (ushort_t*)(w + offB);
    int* rp    = (int*)(w + offRP);
    int* ep    = (int*)(w + offEP);
    int* prp   = (int*)(w + offPRP);
    int* plist = (int*)(w + offPL);
    int* nrp   = (int*)(w + offNRP);
    int* nlist = (int*)(w + offNL);
    int* bsum  = (int*)(w + offBS);
    // cursors borrow bufA (dead until encode)
    int* cur_e = (int*)(w + offA);
    int* cur_p = (int*)(w + offA + 4194304);
    int* cur_n = (int*)(w + offA + 8388608);

    const int TPB = 256;
    int gNSrow = cdiv_l((long)NS_ * 32, TPB);

    // ---- degree histograms ----
    hipMemsetAsync(rp,  0, 2000064, stream);
    hipMemsetAsync(prp, 0, 32832, stream);
    hipMemsetAsync(nrp, 0, 800064, stream);
    k_deg_edges<<<cdiv_l(ES_, TPB), TPB, 0, stream>>>(dstv, rp);
    k_deg_ns<<<cdiv_l(NS_, TPB), TPB, 0, stream>>>(batch_x, nodes_mapper, prp, nrp);
    // ---- scans (edge, patch, node) ----
    k_scan1<<<cdiv_l(NS_, 1024), TPB, 0, stream>>>(rp, bsum, NS_);
    k_scan2<<<1, 512, 0, stream>>>(bsum, cdiv_l(NS_, 1024));
    k_scan3<<<cdiv_l(NS_ + 1, TPB), TPB, 0, stream>>>(rp, bsum, cur_e, NS_, ES_);
    k_scan1<<<cdiv_l(BP_, 1024), TPB, 0, stream>>>(prp, bsum, BP_);
    k_scan2<<<1, 512, 0, stream>>>(bsum, cdiv_l(BP_, 1024));
    k_scan3<<<cdiv_l(BP_ + 1, TPB), TPB, 0, stream>>>(prp, bsum, cur_p, BP_, NS_);
    k_scan1<<<cdiv_l(N_ORIG, 1024), TPB, 0, stream>>>(nrp, bsum, N_ORIG);
    k_scan2<<<1, 512, 0, stream>>>(bsum, cdiv_l(N_ORIG, 1024));
    k_scan3<<<cdiv_l(N_ORIG + 1, TPB), TPB, 0, stream>>>(nrp, bsum, cur_n, N_ORIG, NS_);
    // ---- scatters ----
    k_scatter_edges<<<cdiv_l(ES_, TPB), TPB, 0, stream>>>(srcv, dstv, edge_attr, edges_mapper, cur_e, ep);
    k_scatter_ns<<<cdiv_l(NS_, TPB), TPB, 0, stream>>>(batch_x, nodes_mapper, cur_p, cur_n, plist, nlist);

    // ---- encode (fused with NS gather) ----
    k_encode_gather<<<gNSrow, TPB, 0, stream>>>(x_atom, rw_pe, nodes_mapper, atom_emb,
                                                rw_W, rw_b, bufB);

    ushort_t* cur = bufB;
    ushort_t* oth = bufA;

    for (int i = 0; i < 4; i++){
        if (i > 0){
            ushort_t* pm   = oth;                               // bf16 [BP,128] in dead pong
            ushort_t* subT = (ushort_t*)((char*)oth + 4194304); // bf16 [BP,128]
            k_patch_pool<<<BP_, 128, 0, stream>>>(cur, prp, plist, pm);
            k_gemm128<<<512, TPB, 0, stream>>>(pm, U_W + (i - 1) * D_ * D_,
                                               U_b + (i - 1) * D_, subT, BP_);
            k_gather_add_b<<<gNSrow, TPB, 0, stream>>>((ushort4*)cur, (const ushort4*)subT,
                                                       batch_x, NS_);
            k_node_sync<<<N_ORIG, 128, 0, stream>>>(cur, nrp, nlist);
        }
        k_conv_mfma<<<1024, TPB, 0, stream>>>(cur, oth, rp, ep, bond_emb,
                                              gnn_W + i * D_ * D_, gnn_b + i * D_);
        ushort_t* t = cur; cur = oth; oth = t;
    }

    // ---- patch pooling + mixer (mbuf in dead pong buffer) ----
    float* mbuf = (float*)oth;
    k_patch_pool_sx<<<BP_, 128, 0, stream>>>(cur, prp, plist, patch_pe, prw_W, prw_b, mbuf);

    for (int l = 0; l < 2; l++){
        k_token_mix<<<B_, TPB, 0, stream>>>(mbuf, ln1_g + l * D_, ln1_b + l * D_,
                                            tW1 + l * P_ * TH_, tb1 + l * TH_,
                                            tW2 + l * TH_ * P_, tb2 + l * P_);
        k_channel_mix<<<BP_ / 16, TPB, 0, stream>>>(mbuf, ln2_g + l * D_, ln2_b + l * D_,
                                                    cW1 + l * D_ * CH_, cb1 + l * CH_,
                                                    cW2 + l * CH_ * D_, cb2 + l * D_);
    }
    k_final<<<B_, 128, 0, stream>>>(mbuf, oW1, ob1, oW2, ob2, (float*)d_out);
}

// Round 6
// 2041.240 us; speedup vs baseline: 4.3508x; 1.1345x over previous
//
#include <hip/hip_runtime.h>
#include <hip/hip_bf16.h>
#include <math.h>

#define N_ORIG 200000
#define NS_    500000
#define ES_    1000000
#define B_     256
#define P_     32
#define D_     128
#define BP_    8192
#define RW_    20
#define PRW_   8
#define TH_    64
#define CH_    512

static inline int cdiv_l(long a, long b){ return (int)((a + b - 1) / b); }

typedef unsigned short ushort_t;
typedef __attribute__((ext_vector_type(8))) short gmx_bv8;   // 8 bf16 (4 VGPRs)
typedef __attribute__((ext_vector_type(4))) float gmx_fv4;   // 4 f32 acc

__device__ __forceinline__ float b2f(ushort_t u){
    union { unsigned int i; float f; } c; c.i = ((unsigned int)u) << 16; return c.f;
}
__device__ __forceinline__ ushort_t f2b(float f){
    union { float f; unsigned int u; } c; c.f = f;
    unsigned int u = c.u;
    u += 0x7fffu + ((u >> 16) & 1u);      // RNE
    return (ushort_t)(u >> 16);
}
__device__ __forceinline__ float4 b2f4(ushort4 v){
    return make_float4(b2f(v.x), b2f(v.y), b2f(v.z), b2f(v.w));
}
__device__ __forceinline__ ushort4 f2b4(float4 v){
    ushort4 r; r.x = f2b(v.x); r.y = f2b(v.y); r.z = f2b(v.z); r.w = f2b(v.w); return r;
}

__device__ __forceinline__ float gelu_t(float x){
    float t = tanhf(0.7978845608028654f * (x + 0.044715f * x * x * x));
    return 0.5f * x * (1.0f + t);
}

// ---------------- diagnostics ----------------
__global__ void k_breadcrumb(float* __restrict__ out, int n, float v){
    int i = blockIdx.x * 256 + threadIdx.x;
    if (i < n) out[i] = v;
}

// ---------------- degree histograms ----------------
__global__ void k_deg_edges(const int* __restrict__ dstv, int* __restrict__ deg){
    int e = blockIdx.x * 256 + threadIdx.x;
    if (e >= ES_) return;
    atomicAdd(&deg[dstv[e]], 1);
}

__global__ void k_deg_ns(const int* __restrict__ bx, const int* __restrict__ nm,
                         int* __restrict__ pdeg, int* __restrict__ ndeg){
    int i = blockIdx.x * 256 + threadIdx.x;
    if (i >= NS_) return;
    atomicAdd(&pdeg[bx[i]], 1);
    atomicAdd(&ndeg[nm[i]], 1);
}

// ---------------- generic 3-phase exclusive scan (n <= 512*1024) ----------------
__global__ __launch_bounds__(256)
void k_scan1(int* __restrict__ a, int* __restrict__ bsum, int n){
    __shared__ int sb[256];
    int tid = threadIdx.x;
    long base = (long)blockIdx.x * 1024 + tid * 4;
    int v0 = 0, v1 = 0, v2 = 0, v3 = 0;
    if (base + 0 < n) v0 = a[base + 0];
    if (base + 1 < n) v1 = a[base + 1];
    if (base + 2 < n) v2 = a[base + 2];
    if (base + 3 < n) v3 = a[base + 3];
    int tsum = v0 + v1 + v2 + v3;
    sb[tid] = tsum;
    __syncthreads();
    for (int o = 1; o < 256; o <<= 1){
        int t = (tid >= o) ? sb[tid - o] : 0;
        __syncthreads();
        sb[tid] += t;
        __syncthreads();
    }
    int excl = sb[tid] - tsum;
    if (tid == 255) bsum[blockIdx.x] = sb[255];
    if (base + 0 < n) a[base + 0] = excl;
    if (base + 1 < n) a[base + 1] = excl + v0;
    if (base + 2 < n) a[base + 2] = excl + v0 + v1;
    if (base + 3 < n) a[base + 3] = excl + v0 + v1 + v2;
}

__global__ __launch_bounds__(512)
void k_scan2(int* __restrict__ bsum, int nb){
    __shared__ int sb[512];
    int tid = threadIdx.x;
    int orig = (tid < nb) ? bsum[tid] : 0;
    sb[tid] = orig;
    __syncthreads();
    for (int o = 1; o < 512; o <<= 1){
        int t = (tid >= o) ? sb[tid - o] : 0;
        __syncthreads();
        sb[tid] += t;
        __syncthreads();
    }
    if (tid < nb) bsum[tid] = sb[tid] - orig;
}

__global__ void k_scan3(int* __restrict__ a, const int* __restrict__ bsum,
                        int* __restrict__ cursor, int n, int total){
    long i = (long)blockIdx.x * 256 + threadIdx.x;
    if (i < n){
        int v = a[i] + bsum[i >> 10];
        a[i] = v;
        cursor[i] = v;
    } else if (i == n){
        a[n] = total;
    }
}

// ---------------- CSR scatters ----------------
// epack = orig_src (18 bits) | bond (3 bits) << 18
__global__ void k_scatter_edges(const int* __restrict__ srcv, const int* __restrict__ dstv,
                                const int* __restrict__ ea, const int* __restrict__ em,
                                const int* __restrict__ nm,
                                int* __restrict__ cursor, int* __restrict__ epack){
    int e = blockIdx.x * 256 + threadIdx.x;
    if (e >= ES_) return;
    int pos = atomicAdd(&cursor[dstv[e]], 1);
    epack[pos] = nm[srcv[e]] | (ea[em[e]] << 18);
}

__global__ void k_scatter_ns(const int* __restrict__ bx, const int* __restrict__ nm,
                             int* __restrict__ cur_p, int* __restrict__ cur_n,
                             int* __restrict__ plist, int* __restrict__ nlist){
    int i = blockIdx.x * 256 + threadIdx.x;
    if (i >= NS_) return;
    int pp = atomicAdd(&cur_p[bx[i]], 1);
    plist[pp] = i;
    int pn = atomicAdd(&cur_n[nm[i]], 1);
    nlist[pn] = i;
}

// ---------------- node encoder: xn[n] = atom_emb[xa] + rw @ rwW + rwb (compact) ----------------
__global__ void k_encode(const int* __restrict__ xa, const float* __restrict__ rw,
                         const float* __restrict__ aemb, const float* __restrict__ rwW,
                         const float* __restrict__ rwb, ushort_t* __restrict__ xn){
    long i = (long)blockIdx.x * 256 + threadIdx.x;
    if (i >= (long)N_ORIG * 32) return;
    int n = (int)(i >> 5), q = (int)(i & 31);
    const float4* aemb4 = (const float4*)aemb;
    const float4* rwW4  = (const float4*)rwW;
    const float4* rwb4  = (const float4*)rwb;
    float4 v = aemb4[(long)xa[n] * 32 + q];
    float4 bb = rwb4[q];
    v.x += bb.x; v.y += bb.y; v.z += bb.z; v.w += bb.w;
    const float* rr = rw + (long)n * RW_;
    #pragma unroll
    for (int k = 0; k < RW_; k++){
        float rv = rr[k];
        float4 ww = rwW4[k * 32 + q];
        v.x = fmaf(rv, ww.x, v.x); v.y = fmaf(rv, ww.y, v.y);
        v.z = fmaf(rv, ww.z, v.z); v.w = fmaf(rv, ww.w, v.w);
    }
    ((ushort4*)xn)[i] = f2b4(v);
}

// ---------------- patch pooling via CSR (bf16 mean of per-copy state) ----------------
__global__ __launch_bounds__(128)
void k_patch_pool(const ushort_t* __restrict__ xs, const int* __restrict__ prp,
                  const int* __restrict__ plist, ushort_t* __restrict__ pm){
    int p = blockIdx.x, d = threadIdx.x;
    int j0 = prp[p], j1 = prp[p + 1];
    float s = 0.f;
    for (int j = j0; j < j1; j++) s += b2f(xs[(long)plist[j] * D_ + d]);
    pm[(long)p * D_ + d] = f2b(s / fmaxf((float)(j1 - j0), 1.f));
}

// ---------------- final patch pooling + PE (f32 out) ----------------
__global__ __launch_bounds__(128)
void k_patch_pool_sx(const ushort_t* __restrict__ xs, const int* __restrict__ prp,
                     const int* __restrict__ plist, const float* __restrict__ ppe,
                     const float* __restrict__ pW, const float* __restrict__ pb,
                     float* __restrict__ m){
    int p = blockIdx.x, d = threadIdx.x;
    int j0 = prp[p], j1 = prp[p + 1];
    float s = 0.f;
    for (int j = j0; j < j1; j++) s += b2f(xs[(long)plist[j] * D_ + d]);
    s = s / fmaxf((float)(j1 - j0), 1.f) + pb[d];
    #pragma unroll
    for (int k = 0; k < PRW_; k++) s = fmaf(ppe[p * PRW_ + k], pW[k * D_ + d], s);
    m[(long)p * D_ + d] = s;
}

// ---------------- fused pre-step reduce: xn[n] = mean_copies(xs[j] + subT[bx[j]]) ----------------
__global__ __launch_bounds__(128)
void k_node_resync(const ushort_t* __restrict__ xs, const ushort_t* __restrict__ subT,
                   const int* __restrict__ bx, const int* __restrict__ nrp,
                   const int* __restrict__ nlist, ushort_t* __restrict__ xn){
    int n = blockIdx.x, d = threadIdx.x;
    int j0 = nrp[n], j1 = nrp[n + 1];
    float s = 0.f;
    for (int j = j0; j < j1; j++){
        int r = nlist[j];
        s += b2f(xs[(long)r * D_ + d]) + b2f(subT[(long)bx[r] * D_ + d]);
    }
    xn[(long)n * D_ + d] = f2b(s / fmaxf((float)(j1 - j0), 1.f));
}

// ---------------- U-step GEMM: out_bf16 = relu(in_bf16 @ W + b) ----------------
#define FMA4(AV, BV, AC) { AC[0]=fmaf(AV,BV.x,AC[0]); AC[1]=fmaf(AV,BV.y,AC[1]); AC[2]=fmaf(AV,BV.z,AC[2]); AC[3]=fmaf(AV,BV.w,AC[3]); }

__global__ __launch_bounds__(256)
void k_gemm128(const ushort_t* __restrict__ in1, const float* __restrict__ W,
               const float* __restrict__ bvec, ushort_t* __restrict__ out, int nrows){
    __shared__ ushort_t sW[D_ * D_];    // 32 KB
    __shared__ float sIn[16 * 132];     // 8.25 KB
    int tid = threadIdx.x;
    for (int k = tid; k < D_ * D_; k += 256) sW[k] = f2b(W[k]);
    int jc = (tid & 31) * 4;
    int rr = (tid >> 5) * 2;
    float4 bv = *(const float4*)&bvec[jc];
    const ushort4* in1_4 = (const ushort4*)in1;
    ushort4* out_4 = (ushort4*)out;
    int ntiles = (nrows + 15) / 16;
    for (int tile = blockIdx.x; tile < ntiles; tile += gridDim.x){
        int r0 = tile * 16;
        __syncthreads();
        for (int k = tid; k < 16 * 32; k += 256){
            int r = k >> 5, q = k & 31;
            float4 v = make_float4(0.f, 0.f, 0.f, 0.f);
            if (r0 + r < nrows) v = b2f4(in1_4[(long)(r0 + r) * 32 + q]);
            *(float4*)&sIn[r * 132 + q * 4] = v;
        }
        __syncthreads();
        float acc0[4] = {0.f,0.f,0.f,0.f}, acc1[4] = {0.f,0.f,0.f,0.f};
        for (int k = 0; k < D_; k += 4){
            float4 a0 = *(const float4*)&sIn[(rr + 0) * 132 + k];
            float4 a1 = *(const float4*)&sIn[(rr + 1) * 132 + k];
            float4 b0 = b2f4(*(const ushort4*)&sW[(k + 0) * D_ + jc]);
            float4 b1 = b2f4(*(const ushort4*)&sW[(k + 1) * D_ + jc]);
            float4 b2 = b2f4(*(const ushort4*)&sW[(k + 2) * D_ + jc]);
            float4 b3 = b2f4(*(const ushort4*)&sW[(k + 3) * D_ + jc]);
            FMA4(a0.x, b0, acc0) FMA4(a0.y, b1, acc0) FMA4(a0.z, b2, acc0) FMA4(a0.w, b3, acc0)
            FMA4(a1.x, b0, acc1) FMA4(a1.y, b1, acc1) FMA4(a1.z, b2, acc1) FMA4(a1.w, b3, acc1)
        }
        #define EPILOG(AC, ROFF) { \
            int row = r0 + rr + ROFF; \
            if (row < nrows){ \
                float4 o; \
                o.x = fmaxf(AC[0] + bv.x, 0.f); o.y = fmaxf(AC[1] + bv.y, 0.f); \
                o.z = fmaxf(AC[2] + bv.z, 0.f); o.w = fmaxf(AC[3] + bv.w, 0.f); \
                out_4[(long)row * 32 + (tid & 31)] = f2b4(o); \
            } }
        EPILOG(acc0, 0)
        EPILOG(acc1, 1)
        #undef EPILOG
    }
}

// ---------------- MFMA conv: xs[r] = xn[nm[r]] + relu((xn[nm[r]] + agg_csr) @ W + b) ----------------
// Sources gathered from COMPACT xn (51 MB, L3-resident). epack = orig_src | bond<<18.
#define CROWS 16

__global__ __launch_bounds__(256)
void k_conv_mfma(const ushort_t* __restrict__ xn, const int* __restrict__ nm,
                 ushort_t* __restrict__ xout,
                 const int* __restrict__ rp, const int* __restrict__ epack,
                 const float* __restrict__ bond, const float* __restrict__ W,
                 const float* __restrict__ bvec){
    __shared__ ushort_t sWf[D_ * D_];       // 32 KB fragment-ordered bf16 weights
    __shared__ char sInB[CROWS * 256];      // 4 KB bf16 A-tile (swizzled rows)
    __shared__ ushort_t sSelf[CROWS * D_];  // 4 KB raw self rows (for residual)
    int tid = threadIdx.x;
    // Weight fragments: unit u = (nb*4 + kb)*64 + l, nb=0..7, kb=0..3, l=0..63.
    // Lane l of tile (nb,kb) holds W[kb*32 + 8*(l>>4) + j][nb*16 + (l&15)], j=0..7.
    for (int u = tid; u < 2048; u += 256){
        int l = u & 63, t2 = u >> 6;
        int kb = t2 & 3, nb = t2 >> 2;
        int col = nb * 16 + (l & 15);
        int kr  = kb * 32 + 8 * (l >> 4);
        ushort4 lo, hi;
        lo.x = f2b(W[(kr + 0) * D_ + col]); lo.y = f2b(W[(kr + 1) * D_ + col]);
        lo.z = f2b(W[(kr + 2) * D_ + col]); lo.w = f2b(W[(kr + 3) * D_ + col]);
        hi.x = f2b(W[(kr + 4) * D_ + col]); hi.y = f2b(W[(kr + 5) * D_ + col]);
        hi.z = f2b(W[(kr + 6) * D_ + col]); hi.w = f2b(W[(kr + 7) * D_ + col]);
        *(ushort4*)&sWf[u * 8 + 0] = lo;
        *(ushort4*)&sWf[u * 8 + 4] = hi;
    }
    int wid = tid >> 6, lane = tid & 63;
    int colA = lane & 15, rgrp = lane >> 4;
    int c0 = 32 * wid + colA, c1 = c0 + 16;
    float bias0 = bvec[c0], bias1 = bvec[c1];
    const ushort4* xn4 = (const ushort4*)xn;
    const float4* bond4 = (const float4*)bond;
    const int ntiles = NS_ / CROWS;
    __syncthreads();
    for (int tile = blockIdx.x; tile < ntiles; tile += gridDim.x){
        int r0 = tile * CROWS;
        // ---- stage A = x_self + sum relu(x_src + e); keep raw self for residual ----
        #pragma unroll
        for (int it = 0; it < 2; it++){
            int k = tid + it * 256;
            int r = k >> 5, q = k & 31;
            int row = r0 + r;
            int nself = nm[row];
            ushort4 selfb = xn4[(long)nself * 32 + q];
            *(ushort4*)&sSelf[r * D_ + q * 4] = selfb;
            float4 v = b2f4(selfb);
            int e0 = rp[row], e1 = rp[row + 1];
            for (int e = e0; e < e1; e++){
                int pk = epack[e];
                float4 u = b2f4(xn4[(long)(pk & 0x3FFFF) * 32 + q]);
                float4 bb = bond4[(pk >> 18) * 32 + q];
                v.x += fmaxf(u.x + bb.x, 0.f);
                v.y += fmaxf(u.y + bb.y, 0.f);
                v.z += fmaxf(u.z + bb.z, 0.f);
                v.w += fmaxf(u.w + bb.w, 0.f);
            }
            int off = (r * 256 + q * 8) ^ ((r & 7) << 4);
            *(ushort4*)&sInB[off] = f2b4(v);
        }
        __syncthreads();
        // ---- MFMA: D[16 rows x 32 cols] per wave ----
        gmx_fv4 acc0 = {0.f,0.f,0.f,0.f}, acc1 = {0.f,0.f,0.f,0.f};
        #pragma unroll
        for (int kb = 0; kb < 4; kb++){
            int kslot = kb * 4 + rgrp;
            gmx_bv8 a = *(const gmx_bv8*)&sInB[(colA * 256 + kslot * 16) ^ ((colA & 7) << 4)];
            gmx_bv8 b0 = *(const gmx_bv8*)&sWf[(((2 * wid + 0) * 4 + kb) * 64 + lane) * 8];
            gmx_bv8 b1 = *(const gmx_bv8*)&sWf[(((2 * wid + 1) * 4 + kb) * 64 + lane) * 8];
            acc0 = __builtin_amdgcn_mfma_f32_16x16x32_bf16(a, b0, acc0, 0, 0, 0);
            acc1 = __builtin_amdgcn_mfma_f32_16x16x32_bf16(a, b1, acc1, 0, 0, 0);
        }
        // ---- epilogue: D row = rgrp*4 + ri, col = c0/c1; residual from sSelf ----
        #pragma unroll
        for (int ri = 0; ri < 4; ri++){
            int prow = rgrp * 4 + ri;
            long base = (long)(r0 + prow) * D_;
            float o0 = b2f(sSelf[prow * D_ + c0]) + fmaxf(acc0[ri] + bias0, 0.f);
            float o1 = b2f(sSelf[prow * D_ + c1]) + fmaxf(acc1[ri] + bias1, 0.f);
            xout[base + c0] = f2b(o0);
            xout[base + c1] = f2b(o1);
        }
        __syncthreads();
    }
}

// ---------------- mixer: token mixing (one block per graph) ----------------
__global__ __launch_bounds__(256)
void k_token_mix(float* __restrict__ m, const float* __restrict__ g, const float* __restrict__ be,
                 const float* __restrict__ tW1, const float* __restrict__ tb1,
                 const float* __restrict__ tW2, const float* __restrict__ tb2){
    __shared__ float sy[P_][D_];        // 16 KB
    __shared__ float sh[D_][TH_ + 1];   // 33.3 KB
    int b = blockIdx.x, tid = threadIdx.x;
    float* mb = m + (long)b * P_ * D_;
    int wv = tid >> 6, ln_ = tid & 63;
    for (int r = wv; r < P_; r += 4){
        float v0 = mb[r * D_ + ln_], v1 = mb[r * D_ + 64 + ln_];
        float s = v0 + v1, ss = v0 * v0 + v1 * v1;
        #pragma unroll
        for (int o = 32; o > 0; o >>= 1){ s += __shfl_down(s, o, 64); ss += __shfl_down(ss, o, 64); }
        s = __shfl(s, 0, 64); ss = __shfl(ss, 0, 64);
        float mu = s * (1.f / 128.f);
        float var = ss * (1.f / 128.f) - mu * mu;
        float rs = rsqrtf(var + 1e-5f);
        sy[r][ln_]      = (v0 - mu) * rs * g[ln_]      + be[ln_];
        sy[r][64 + ln_] = (v1 - mu) * rs * g[64 + ln_] + be[64 + ln_];
    }
    __syncthreads();
    for (int o = tid; o < D_ * TH_; o += 256){
        int t = o & 63, d = o >> 6;
        float a = tb1[t];
        #pragma unroll
        for (int p = 0; p < P_; p++) a = fmaf(sy[p][d], tW1[p * TH_ + t], a);
        sh[d][t] = gelu_t(a);
    }
    __syncthreads();
    for (int o = tid; o < P_ * D_; o += 256){
        int d = o & 127, p = o >> 7;
        float a = tb2[p];
        #pragma unroll
        for (int t = 0; t < TH_; t++) a = fmaf(sh[d][t], tW2[t * P_ + p], a);
        mb[p * D_ + d] += a;
    }
}

// ---------------- mixer: channel mixing (16 rows per block) ----------------
__global__ __launch_bounds__(256)
void k_channel_mix(float* __restrict__ m, const float* __restrict__ g, const float* __restrict__ be,
                   const float* __restrict__ cW1, const float* __restrict__ cb1,
                   const float* __restrict__ cW2, const float* __restrict__ cb2){
    __shared__ float sy[16][D_];        // 8 KB
    __shared__ float sh[16][CH_ + 1];   // 32.8 KB
    int r0 = blockIdx.x * 16, tid = threadIdx.x;
    int wv = tid >> 6, ln_ = tid & 63;
    for (int r = wv; r < 16; r += 4){
        float v0 = m[(long)(r0 + r) * D_ + ln_], v1 = m[(long)(r0 + r) * D_ + 64 + ln_];
        float s = v0 + v1, ss = v0 * v0 + v1 * v1;
        #pragma unroll
        for (int o = 32; o > 0; o >>= 1){ s += __shfl_down(s, o, 64); ss += __shfl_down(ss, o, 64); }
        s = __shfl(s, 0, 64); ss = __shfl(ss, 0, 64);
        float mu = s * (1.f / 128.f);
        float var = ss * (1.f / 128.f) - mu * mu;
        float rs = rsqrtf(var + 1e-5f);
        sy[r][ln_]      = (v0 - mu) * rs * g[ln_]      + be[ln_];
        sy[r][64 + ln_] = (v1 - mu) * rs * g[64 + ln_] + be[64 + ln_];
    }
    __syncthreads();
    #pragma unroll
    for (int th = 0; th < 2; th++){
        int t = tid + th * 256;
        float acc[16];
        #pragma unroll
        for (int r = 0; r < 16; r++) acc[r] = cb1[t];
        for (int k = 0; k < D_; k++){
            float w = cW1[k * CH_ + t];
            #pragma unroll
            for (int r = 0; r < 16; r++) acc[r] = fmaf(sy[r][k], w, acc[r]);
        }
        #pragma unroll
        for (int r = 0; r < 16; r++) sh[r][t] = gelu_t(acc[r]);
    }
    __syncthreads();
    {
        int d = tid & 127, rbase = tid >> 7;
        float acc[8];
        #pragma unroll
        for (int q = 0; q < 8; q++) acc[q] = 0.f;
        for (int t = 0; t < CH_; t++){
            float w = cW2[t * D_ + d];
            #pragma unroll
            for (int q = 0; q < 8; q++) acc[q] = fmaf(sh[rbase + 2 * q][t], w, acc[q]);
        }
        float cb = cb2[d];
        #pragma unroll
        for (int q = 0; q < 8; q++){
            int row = r0 + rbase + 2 * q;
            m[(long)row * D_ + d] += acc[q] + cb;
        }
    }
}

// ---------------- final pooled head ----------------
__global__ __launch_bounds__(128)
void k_final(const float* __restrict__ m, const float* __restrict__ oW1, const float* __restrict__ ob1,
             const float* __restrict__ oW2, const float* __restrict__ ob2, float* __restrict__ out){
    __shared__ float sp[D_];
    __shared__ float red[128];
    int b = blockIdx.x, tid = threadIdx.x;
    float a = 0.f;
    for (int p = 0; p < P_; p++) a += m[(long)b * P_ * D_ + p * D_ + tid];
    sp[tid] = a * (1.0f / P_);
    __syncthreads();
    float h = ob1[tid];
    for (int d = 0; d < D_; d++) h = fmaf(sp[d], oW1[d * D_ + tid], h);
    h = fmaxf(h, 0.f) * oW2[tid];
    red[tid] = h;
    __syncthreads();
    for (int s = 64; s > 0; s >>= 1){
        if (tid < s) red[tid] += red[tid + s];
        __syncthreads();
    }
    if (tid == 0) out[b] = red[0] + ob2[0];
}

extern "C" void kernel_launch(void* const* d_in, const int* in_sizes, int n_in,
                              void* d_out, int out_size, void* d_ws, size_t ws_size,
                              hipStream_t stream){
    const int*   x_atom       = (const int*)  d_in[0];
    const float* rw_pe        = (const float*)d_in[1];
    const int*   edge_attr    = (const int*)  d_in[2];
    const int*   nodes_mapper = (const int*)  d_in[3];
    const int*   edges_mapper = (const int*)  d_in[4];
    const int*   edge_index   = (const int*)  d_in[5];
    const int*   batch_x      = (const int*)  d_in[6];
    const float* patch_pe     = (const float*)d_in[7];
    // d_in[8] = mask, all-true by construction -> mean pooling
    const float* atom_emb = (const float*)d_in[9];
    const float* bond_emb = (const float*)d_in[10];
    const float* rw_W  = (const float*)d_in[11];
    const float* rw_b  = (const float*)d_in[12];
    const float* prw_W = (const float*)d_in[13];
    const float* prw_b = (const float*)d_in[14];
    const float* gnn_W = (const float*)d_in[15];
    const float* gnn_b = (const float*)d_in[16];
    const float* U_W   = (const float*)d_in[17];
    const float* U_b   = (const float*)d_in[18];
    const float* ln1_g = (const float*)d_in[19];
    const float* ln1_b = (const float*)d_in[20];
    const float* tW1   = (const float*)d_in[21];
    const float* tb1   = (const float*)d_in[22];
    const float* tW2   = (const float*)d_in[23];
    const float* tb2   = (const float*)d_in[24];
    const float* ln2_g = (const float*)d_in[25];
    const float* ln2_b = (const float*)d_in[26];
    const float* cW1   = (const float*)d_in[27];
    const float* cb1   = (const float*)d_in[28];
    const float* cW2   = (const float*)d_in[29];
    const float* cb2   = (const float*)d_in[30];
    const float* oW1   = (const float*)d_in[31];
    const float* ob1   = (const float*)d_in[32];
    const float* oW2   = (const float*)d_in[33];
    const float* ob2   = (const float*)d_in[34];

    const int* srcv = edge_index;
    const int* dstv = edge_index + ES_;

    // ---- workspace layout: ~198.5 MB <= 256 MiB ----
    char* w = (char*)d_ws;
    size_t offXS  = 0;                                        // per-copy state [NS,128] bf16
    size_t offXN  = offXS  + (size_t)NS_ * D_ * 2;            // 128,000,000: compact [N,128] bf16
    size_t offRP  = offXN  + (size_t)N_ORIG * D_ * 2;         // 179,200,000
    size_t offEP  = offRP  + 2000064;
    size_t offPRP = offEP  + (size_t)ES_ * 4;
    size_t offPL  = offPRP + 32832;
    size_t offNRP = offPL  + (size_t)NS_ * 4;
    size_t offNL  = offNRP + 800064;
    size_t offBS  = offNL  + (size_t)NS_ * 4;
    size_t offPM  = offBS  + 2048;                            // pm bf16 [BP,128]
    size_t offST  = offPM  + (size_t)BP_ * D_ * 2;            // subT bf16 [BP,128]
    size_t offM   = offST  + (size_t)BP_ * D_ * 2;            // mbuf f32 [BP,128]
    size_t needed = offM   + (size_t)BP_ * D_ * 4;            // ~198.5 MB

    if (ws_size < needed){
        k_breadcrumb<<<cdiv_l(out_size, 256), 256, 0, stream>>>((float*)d_out, out_size,
                                                                (float)(ws_size >> 20));
        return;
    }

    // canary: absmax ≈ 6.7 -> pipeline died mid-way; ≈ 0.32 -> module never ran
    k_breadcrumb<<<cdiv_l(out_size, 256), 256, 0, stream>>>((float*)d_out, out_size, 7.0f);

    ushort_t* xs = (ushort_t*)(w + offXS);
    ushort_t* xn = (ushort_t*)(w + offXN);
    int* rp    = (int*)(w + offRP);
    int* ep    = (int*)(w + offEP);
    int* prp   = (int*)(w + offPRP);
    int* plist = (int*)(w + offPL);
    int* nrp   = (int*)(w + offNRP);
    int* nlist = (int*)(w + offNL);
    int* bsum  = (int*)(w + offBS);
    ushort_t* pm   = (ushort_t*)(w + offPM);
    ushort_t* subT = (ushort_t*)(w + offST);
    float*    mbuf = (float*)(w + offM);
    // cursors borrow xs (dead until conv 0 writes it)
    int* cur_e = (int*)(w + offXS);
    int* cur_p = (int*)(w + offXS + 4194304);
    int* cur_n = (int*)(w + offXS + 8388608);

    const int TPB = 256;

    // ---- degree histograms ----
    hipMemsetAsync(rp,  0, 2000064, stream);
    hipMemsetAsync(prp, 0, 32832, stream);
    hipMemsetAsync(nrp, 0, 800064, stream);
    k_deg_edges<<<cdiv_l(ES_, TPB), TPB, 0, stream>>>(dstv, rp);
    k_deg_ns<<<cdiv_l(NS_, TPB), TPB, 0, stream>>>(batch_x, nodes_mapper, prp, nrp);
    // ---- scans (edge, patch, node) ----
    k_scan1<<<cdiv_l(NS_, 1024), TPB, 0, stream>>>(rp, bsum, NS_);
    k_scan2<<<1, 512, 0, stream>>>(bsum, cdiv_l(NS_, 1024));
    k_scan3<<<cdiv_l(NS_ + 1, TPB), TPB, 0, stream>>>(rp, bsum, cur_e, NS_, ES_);
    k_scan1<<<cdiv_l(BP_, 1024), TPB, 0, stream>>>(prp, bsum, BP_);
    k_scan2<<<1, 512, 0, stream>>>(bsum, cdiv_l(BP_, 1024));
    k_scan3<<<cdiv_l(BP_ + 1, TPB), TPB, 0, stream>>>(prp, bsum, cur_p, BP_, NS_);
    k_scan1<<<cdiv_l(N_ORIG, 1024), TPB, 0, stream>>>(nrp, bsum, N_ORIG);
    k_scan2<<<1, 512, 0, stream>>>(bsum, cdiv_l(N_ORIG, 1024));
    k_scan3<<<cdiv_l(N_ORIG + 1, TPB), TPB, 0, stream>>>(nrp, bsum, cur_n, N_ORIG, NS_);
    // ---- scatters ----
    k_scatter_edges<<<cdiv_l(ES_, TPB), TPB, 0, stream>>>(srcv, dstv, edge_attr, edges_mapper,
                                                          nodes_mapper, cur_e, ep);
    k_scatter_ns<<<cdiv_l(NS_, TPB), TPB, 0, stream>>>(batch_x, nodes_mapper, cur_p, cur_n, plist, nlist);

    // ---- encode (compact, N rows) ----
    k_encode<<<cdiv_l((long)N_ORIG * 32, TPB), TPB, 0, stream>>>(x_atom, rw_pe, atom_emb,
                                                                 rw_W, rw_b, xn);

    for (int i = 0; i < 4; i++){
        if (i > 0){
            k_patch_pool<<<BP_, 128, 0, stream>>>(xs, prp, plist, pm);
            k_gemm128<<<512, TPB, 0, stream>>>(pm, U_W + (i - 1) * D_ * D_,
                                               U_b + (i - 1) * D_, subT, BP_);
            k_node_resync<<<N_ORIG, 128, 0, stream>>>(xs, subT, batch_x, nrp, nlist, xn);
        }
        k_conv_mfma<<<1024, TPB, 0, stream>>>(xn, nodes_mapper, xs, rp, ep, bond_emb,
                                              gnn_W + i * D_ * D_, gnn_b + i * D_);
    }

    // ---- patch pooling + mixer ----
    k_patch_pool_sx<<<BP_, 128, 0, stream>>>(xs, prp, plist, patch_pe, prw_W, prw_b, mbuf);

    for (int l = 0; l < 2; l++){
        k_token_mix<<<B_, TPB, 0, stream>>>(mbuf, ln1_g + l * D_, ln1_b + l * D_,
                                            tW1 + l * P_ * TH_, tb1 + l * TH_,
                                            tW2 + l * TH_ * P_, tb2 + l * P_);
        k_channel_mix<<<BP_ / 16, TPB, 0, stream>>>(mbuf, ln2_g + l * D_, ln2_b + l * D_,
                                                    cW1 + l * D_ * CH_, cb1 + l * CH_,
                                                    cW2 + l * CH_ * D_, cb2 + l * D_);
    }
    k_final<<<B_, 128, 0, stream>>>(mbuf, oW1, ob1, oW2, ob2, (float*)d_out);
}

// Round 7
// 1976.759 us; speedup vs baseline: 4.4927x; 1.0326x over previous
//
#include <hip/hip_runtime.h>
#include <hip/hip_bf16.h>
#include <math.h>

#define N_ORIG 200000
#define NS_    500000
#define ES_    1000000
#define B_     256
#define P_     32
#define D_     128
#define BP_    8192
#define RW_    20
#define PRW_   8
#define TH_    64
#define CH_    512

static inline int cdiv_l(long a, long b){ return (int)((a + b - 1) / b); }

typedef unsigned short ushort_t;
typedef __attribute__((ext_vector_type(8))) short gmx_bv8;   // 8 bf16 (4 VGPRs)
typedef __attribute__((ext_vector_type(4))) float gmx_fv4;   // 4 f32 acc

__device__ __forceinline__ float b2f(ushort_t u){
    union { unsigned int i; float f; } c; c.i = ((unsigned int)u) << 16; return c.f;
}
__device__ __forceinline__ ushort_t f2b(float f){
    union { float f; unsigned int u; } c; c.f = f;
    unsigned int u = c.u;
    u += 0x7fffu + ((u >> 16) & 1u);      // RNE
    return (ushort_t)(u >> 16);
}
__device__ __forceinline__ float4 b2f4(ushort4 v){
    return make_float4(b2f(v.x), b2f(v.y), b2f(v.z), b2f(v.w));
}
__device__ __forceinline__ ushort4 f2b4(float4 v){
    ushort4 r; r.x = f2b(v.x); r.y = f2b(v.y); r.z = f2b(v.z); r.w = f2b(v.w); return r;
}

__device__ __forceinline__ float gelu_t(float x){
    float t = tanhf(0.7978845608028654f * (x + 0.044715f * x * x * x));
    return 0.5f * x * (1.0f + t);
}

// ---------------- diagnostics ----------------
__global__ void k_breadcrumb(float* __restrict__ out, int n, float v){
    int i = blockIdx.x * 256 + threadIdx.x;
    if (i < n) out[i] = v;
}

// ---------------- degree histograms ----------------
// edge degrees over RELABELED dst (needs perm) — launched after k_scatter_ns
__global__ void k_deg_edges(const int* __restrict__ dstv, const int* __restrict__ perm,
                            int* __restrict__ deg){
    int e = blockIdx.x * 256 + threadIdx.x;
    if (e >= ES_) return;
    atomicAdd(&deg[perm[dstv[e]]], 1);
}

__global__ void k_deg_ns(const int* __restrict__ bx, const int* __restrict__ nm,
                         int* __restrict__ pdeg, int* __restrict__ ndeg){
    int i = blockIdx.x * 256 + threadIdx.x;
    if (i >= NS_) return;
    atomicAdd(&pdeg[bx[i]], 1);
    atomicAdd(&ndeg[nm[i]], 1);
}

// ---------------- generic 3-phase exclusive scan (n <= 512*1024) ----------------
__global__ __launch_bounds__(256)
void k_scan1(int* __restrict__ a, int* __restrict__ bsum, int n){
    __shared__ int sb[256];
    int tid = threadIdx.x;
    long base = (long)blockIdx.x * 1024 + tid * 4;
    int v0 = 0, v1 = 0, v2 = 0, v3 = 0;
    if (base + 0 < n) v0 = a[base + 0];
    if (base + 1 < n) v1 = a[base + 1];
    if (base + 2 < n) v2 = a[base + 2];
    if (base + 3 < n) v3 = a[base + 3];
    int tsum = v0 + v1 + v2 + v3;
    sb[tid] = tsum;
    __syncthreads();
    for (int o = 1; o < 256; o <<= 1){
        int t = (tid >= o) ? sb[tid - o] : 0;
        __syncthreads();
        sb[tid] += t;
        __syncthreads();
    }
    int excl = sb[tid] - tsum;
    if (tid == 255) bsum[blockIdx.x] = sb[255];
    if (base + 0 < n) a[base + 0] = excl;
    if (base + 1 < n) a[base + 1] = excl + v0;
    if (base + 2 < n) a[base + 2] = excl + v0 + v1;
    if (base + 3 < n) a[base + 3] = excl + v0 + v1 + v2;
}

__global__ __launch_bounds__(512)
void k_scan2(int* __restrict__ bsum, int nb){
    __shared__ int sb[512];
    int tid = threadIdx.x;
    int orig = (tid < nb) ? bsum[tid] : 0;
    sb[tid] = orig;
    __syncthreads();
    for (int o = 1; o < 512; o <<= 1){
        int t = (tid >= o) ? sb[tid - o] : 0;
        __syncthreads();
        sb[tid] += t;
        __syncthreads();
    }
    if (tid < nb) bsum[tid] = sb[tid] - orig;
}

__global__ void k_scan3(int* __restrict__ a, const int* __restrict__ bsum,
                        int* __restrict__ cursor, int n, int total){
    long i = (long)blockIdx.x * 256 + threadIdx.x;
    if (i < n){
        int v = a[i] + bsum[i >> 10];
        a[i] = v;
        cursor[i] = v;
    } else if (i == n){
        a[n] = total;
    }
}

// ---------------- CSR scatters ----------------
// Relabel copies patch-major: perm[old] = new; bx2/nm2 indexed by new id;
// nlist stores NEW ids.
__global__ void k_scatter_ns(const int* __restrict__ bx, const int* __restrict__ nm,
                             int* __restrict__ cur_p, int* __restrict__ cur_n,
                             int* __restrict__ perm, int* __restrict__ bx2,
                             int* __restrict__ nm2, int* __restrict__ nlist){
    int i = blockIdx.x * 256 + threadIdx.x;
    if (i >= NS_) return;
    int b = bx[i], n = nm[i];
    int pp = atomicAdd(&cur_p[b], 1);
    perm[i] = pp;
    bx2[pp] = b;
    nm2[pp] = n;
    int pn = atomicAdd(&cur_n[n], 1);
    nlist[pn] = pp;
}

// epack = compact_src (18 bits) | bond (3 bits) << 18 ; dst relabeled via perm
__global__ void k_scatter_edges(const int* __restrict__ srcv, const int* __restrict__ dstv,
                                const int* __restrict__ ea, const int* __restrict__ em,
                                const int* __restrict__ nm, const int* __restrict__ perm,
                                int* __restrict__ cursor, int* __restrict__ epack){
    int e = blockIdx.x * 256 + threadIdx.x;
    if (e >= ES_) return;
    int pos = atomicAdd(&cursor[perm[dstv[e]]], 1);
    epack[pos] = nm[srcv[e]] | (ea[em[e]] << 18);
}

// ---------------- node encoder: xn[n] = atom_emb[xa] + rw @ rwW + rwb (compact) ----------------
__global__ void k_encode(const int* __restrict__ xa, const float* __restrict__ rw,
                         const float* __restrict__ aemb, const float* __restrict__ rwW,
                         const float* __restrict__ rwb, ushort_t* __restrict__ xn){
    long i = (long)blockIdx.x * 256 + threadIdx.x;
    if (i >= (long)N_ORIG * 32) return;
    int n = (int)(i >> 5), q = (int)(i & 31);
    const float4* aemb4 = (const float4*)aemb;
    const float4* rwW4  = (const float4*)rwW;
    const float4* rwb4  = (const float4*)rwb;
    float4 v = aemb4[(long)xa[n] * 32 + q];
    float4 bb = rwb4[q];
    v.x += bb.x; v.y += bb.y; v.z += bb.z; v.w += bb.w;
    const float* rr = rw + (long)n * RW_;
    #pragma unroll
    for (int k = 0; k < RW_; k++){
        float rv = rr[k];
        float4 ww = rwW4[k * 32 + q];
        v.x = fmaf(rv, ww.x, v.x); v.y = fmaf(rv, ww.y, v.y);
        v.z = fmaf(rv, ww.z, v.z); v.w = fmaf(rv, ww.w, v.w);
    }
    ((ushort4*)xn)[i] = f2b4(v);
}

// ---------------- patch pooling (SEQUENTIAL rows thanks to patch-major xs) ----------------
__global__ __launch_bounds__(128)
void k_patch_pool(const ushort_t* __restrict__ xs, const int* __restrict__ prp,
                  ushort_t* __restrict__ pm){
    int p = blockIdx.x, d = threadIdx.x;
    int j0 = prp[p], j1 = prp[p + 1];
    float s0 = 0.f, s1 = 0.f;
    int j = j0;
    for (; j + 1 < j1; j += 2){
        s0 += b2f(xs[(long)j * D_ + d]);
        s1 += b2f(xs[(long)(j + 1) * D_ + d]);
    }
    if (j < j1) s0 += b2f(xs[(long)j * D_ + d]);
    pm[(long)p * D_ + d] = f2b((s0 + s1) / fmaxf((float)(j1 - j0), 1.f));
}

// ---------------- final patch pooling + PE (f32 out, sequential) ----------------
__global__ __launch_bounds__(128)
void k_patch_pool_sx(const ushort_t* __restrict__ xs, const int* __restrict__ prp,
                     const float* __restrict__ ppe, const float* __restrict__ pW,
                     const float* __restrict__ pb, float* __restrict__ m){
    int p = blockIdx.x, d = threadIdx.x;
    int j0 = prp[p], j1 = prp[p + 1];
    float s0 = 0.f, s1 = 0.f;
    int j = j0;
    for (; j + 1 < j1; j += 2){
        s0 += b2f(xs[(long)j * D_ + d]);
        s1 += b2f(xs[(long)(j + 1) * D_ + d]);
    }
    if (j < j1) s0 += b2f(xs[(long)j * D_ + d]);
    float s = (s0 + s1) / fmaxf((float)(j1 - j0), 1.f) + pb[d];
    #pragma unroll
    for (int k = 0; k < PRW_; k++) s = fmaf(ppe[p * PRW_ + k], pW[k * D_ + d], s);
    m[(long)p * D_ + d] = s;
}

// ---------------- fused pre-step reduce: xn[n] = mean_copies(xs[j] + subT[bx2[j]]) ----------------
__global__ __launch_bounds__(128)
void k_node_resync(const ushort_t* __restrict__ xs, const ushort_t* __restrict__ subT,
                   const int* __restrict__ bx2, const int* __restrict__ nrp,
                   const int* __restrict__ nlist, ushort_t* __restrict__ xn){
    int n = blockIdx.x, d = threadIdx.x;
    int j0 = nrp[n], j1 = nrp[n + 1];
    float s = 0.f;
    for (int j = j0; j < j1; j++){
        int r = nlist[j];
        s += b2f(xs[(long)r * D_ + d]) + b2f(subT[(long)bx2[r] * D_ + d]);
    }
    xn[(long)n * D_ + d] = f2b(s / fmaxf((float)(j1 - j0), 1.f));
}

// ---------------- U-step GEMM: out_bf16 = relu(in_bf16 @ W + b) ----------------
#define FMA4(AV, BV, AC) { AC[0]=fmaf(AV,BV.x,AC[0]); AC[1]=fmaf(AV,BV.y,AC[1]); AC[2]=fmaf(AV,BV.z,AC[2]); AC[3]=fmaf(AV,BV.w,AC[3]); }

__global__ __launch_bounds__(256)
void k_gemm128(const ushort_t* __restrict__ in1, const float* __restrict__ W,
               const float* __restrict__ bvec, ushort_t* __restrict__ out, int nrows){
    __shared__ ushort_t sW[D_ * D_];    // 32 KB
    __shared__ float sIn[16 * 132];     // 8.25 KB
    int tid = threadIdx.x;
    for (int k = tid; k < D_ * D_; k += 256) sW[k] = f2b(W[k]);
    int jc = (tid & 31) * 4;
    int rr = (tid >> 5) * 2;
    float4 bv = *(const float4*)&bvec[jc];
    const ushort4* in1_4 = (const ushort4*)in1;
    ushort4* out_4 = (ushort4*)out;
    int ntiles = (nrows + 15) / 16;
    for (int tile = blockIdx.x; tile < ntiles; tile += gridDim.x){
        int r0 = tile * 16;
        __syncthreads();
        for (int k = tid; k < 16 * 32; k += 256){
            int r = k >> 5, q = k & 31;
            float4 v = make_float4(0.f, 0.f, 0.f, 0.f);
            if (r0 + r < nrows) v = b2f4(in1_4[(long)(r0 + r) * 32 + q]);
            *(float4*)&sIn[r * 132 + q * 4] = v;
        }
        __syncthreads();
        float acc0[4] = {0.f,0.f,0.f,0.f}, acc1[4] = {0.f,0.f,0.f,0.f};
        for (int k = 0; k < D_; k += 4){
            float4 a0 = *(const float4*)&sIn[(rr + 0) * 132 + k];
            float4 a1 = *(const float4*)&sIn[(rr + 1) * 132 + k];
            float4 b0 = b2f4(*(const ushort4*)&sW[(k + 0) * D_ + jc]);
            float4 b1 = b2f4(*(const ushort4*)&sW[(k + 1) * D_ + jc]);
            float4 b2 = b2f4(*(const ushort4*)&sW[(k + 2) * D_ + jc]);
            float4 b3 = b2f4(*(const ushort4*)&sW[(k + 3) * D_ + jc]);
            FMA4(a0.x, b0, acc0) FMA4(a0.y, b1, acc0) FMA4(a0.z, b2, acc0) FMA4(a0.w, b3, acc0)
            FMA4(a1.x, b0, acc1) FMA4(a1.y, b1, acc1) FMA4(a1.z, b2, acc1) FMA4(a1.w, b3, acc1)
        }
        #define EPILOG(AC, ROFF) { \
            int row = r0 + rr + ROFF; \
            if (row < nrows){ \
                float4 o; \
                o.x = fmaxf(AC[0] + bv.x, 0.f); o.y = fmaxf(AC[1] + bv.y, 0.f); \
                o.z = fmaxf(AC[2] + bv.z, 0.f); o.w = fmaxf(AC[3] + bv.w, 0.f); \
                out_4[(long)row * 32 + (tid & 31)] = f2b4(o); \
            } }
        EPILOG(acc0, 0)
        EPILOG(acc1, 1)
        #undef EPILOG
    }
}

// ---------------- MFMA conv: xs[r] = xn[nm2[r]] + relu((xn[nm2[r]] + agg_csr) @ W + b) ----------------
// B-fragments live in VGPRs (8 per wave); LDS only 8 KB -> high occupancy.
#define CROWS 16

__global__ __launch_bounds__(256)
void k_conv_mfma(const ushort_t* __restrict__ xn, const int* __restrict__ nm2,
                 ushort_t* __restrict__ xout,
                 const int* __restrict__ rp, const int* __restrict__ epack,
                 const float* __restrict__ bond, const float* __restrict__ W,
                 const float* __restrict__ bvec){
    __shared__ char sInB[CROWS * 256];      // 4 KB bf16 A-tile (swizzled rows)
    __shared__ ushort_t sSelf[CROWS * D_];  // 4 KB raw self rows (for residual)
    int tid = threadIdx.x;
    int wid = tid >> 6, lane = tid & 63;
    int colA = lane & 15, rgrp = lane >> 4;
    int c0 = 32 * wid + colA, c1 = c0 + 16;
    float bias0 = bvec[c0], bias1 = bvec[c1];
    // B fragments in registers: lane l of tile (nb,kb) holds
    // W[kb*32 + 8*rgrp + j][nb*16 + colA], j=0..7; nb = 2*wid (->c0), 2*wid+1 (->c1).
    union { gmx_bv8 v; short s[8]; } bf0[4], bf1[4];
    #pragma unroll
    for (int kb = 0; kb < 4; kb++){
        int kr = kb * 32 + 8 * rgrp;
        #pragma unroll
        for (int j = 0; j < 8; j++){
            bf0[kb].s[j] = (short)f2b(W[(kr + j) * D_ + c0]);
            bf1[kb].s[j] = (short)f2b(W[(kr + j) * D_ + c1]);
        }
    }
    const ushort4* xn4 = (const ushort4*)xn;
    const float4* bond4 = (const float4*)bond;
    const int ntiles = NS_ / CROWS;
    for (int tile = blockIdx.x; tile < ntiles; tile += gridDim.x){
        int r0 = tile * CROWS;
        // ---- stage A = x_self + sum relu(x_src + e); keep raw self for residual ----
        #pragma unroll
        for (int it = 0; it < 2; it++){
            int k = tid + it * 256;
            int r = k >> 5, q = k & 31;
            int row = r0 + r;
            int nself = nm2[row];
            ushort4 selfb = xn4[(long)nself * 32 + q];
            *(ushort4*)&sSelf[r * D_ + q * 4] = selfb;
            float4 v = b2f4(selfb);
            int e0 = rp[row], e1 = rp[row + 1];
            for (int e = e0; e < e1; e++){
                int pk = epack[e];
                float4 u = b2f4(xn4[(long)(pk & 0x3FFFF) * 32 + q]);
                float4 bb = bond4[(pk >> 18) * 32 + q];
                v.x += fmaxf(u.x + bb.x, 0.f);
                v.y += fmaxf(u.y + bb.y, 0.f);
                v.z += fmaxf(u.z + bb.z, 0.f);
                v.w += fmaxf(u.w + bb.w, 0.f);
            }
            int off = (r * 256 + q * 8) ^ ((r & 7) << 4);
            *(ushort4*)&sInB[off] = f2b4(v);
        }
        __syncthreads();
        // ---- MFMA: D[16 rows x 32 cols] per wave ----
        gmx_fv4 acc0 = {0.f,0.f,0.f,0.f}, acc1 = {0.f,0.f,0.f,0.f};
        #pragma unroll
        for (int kb = 0; kb < 4; kb++){
            int kslot = kb * 4 + rgrp;
            gmx_bv8 a = *(const gmx_bv8*)&sInB[(colA * 256 + kslot * 16) ^ ((colA & 7) << 4)];
            acc0 = __builtin_amdgcn_mfma_f32_16x16x32_bf16(a, bf0[kb].v, acc0, 0, 0, 0);
            acc1 = __builtin_amdgcn_mfma_f32_16x16x32_bf16(a, bf1[kb].v, acc1, 0, 0, 0);
        }
        // ---- epilogue: D row = rgrp*4 + ri, col = c0/c1; residual from sSelf ----
        #pragma unroll
        for (int ri = 0; ri < 4; ri++){
            int prow = rgrp * 4 + ri;
            long base = (long)(r0 + prow) * D_;
            float o0 = b2f(sSelf[prow * D_ + c0]) + fmaxf(acc0[ri] + bias0, 0.f);
            float o1 = b2f(sSelf[prow * D_ + c1]) + fmaxf(acc1[ri] + bias1, 0.f);
            xout[base + c0] = f2b(o0);
            xout[base + c1] = f2b(o1);
        }
        __syncthreads();
    }
}

// ---------------- mixer: token mixing (one block per graph) ----------------
__global__ __launch_bounds__(256)
void k_token_mix(float* __restrict__ m, const float* __restrict__ g, const float* __restrict__ be,
                 const float* __restrict__ tW1, const float* __restrict__ tb1,
                 const float* __restrict__ tW2, const float* __restrict__ tb2){
    __shared__ float sy[P_][D_];        // 16 KB
    __shared__ float sh[D_][TH_ + 1];   // 33.3 KB
    int b = blockIdx.x, tid = threadIdx.x;
    float* mb = m + (long)b * P_ * D_;
    int wv = tid >> 6, ln_ = tid & 63;
    for (int r = wv; r < P_; r += 4){
        float v0 = mb[r * D_ + ln_], v1 = mb[r * D_ + 64 + ln_];
        float s = v0 + v1, ss = v0 * v0 + v1 * v1;
        #pragma unroll
        for (int o = 32; o > 0; o >>= 1){ s += __shfl_down(s, o, 64); ss += __shfl_down(ss, o, 64); }
        s = __shfl(s, 0, 64); ss = __shfl(ss, 0, 64);
        float mu = s * (1.f / 128.f);
        float var = ss * (1.f / 128.f) - mu * mu;
        float rs = rsqrtf(var + 1e-5f);
        sy[r][ln_]      = (v0 - mu) * rs * g[ln_]      + be[ln_];
        sy[r][64 + ln_] = (v1 - mu) * rs * g[64 + ln_] + be[64 + ln_];
    }
    __syncthreads();
    for (int o = tid; o < D_ * TH_; o += 256){
        int t = o & 63, d = o >> 6;
        float a = tb1[t];
        #pragma unroll
        for (int p = 0; p < P_; p++) a = fmaf(sy[p][d], tW1[p * TH_ + t], a);
        sh[d][t] = gelu_t(a);
    }
    __syncthreads();
    for (int o = tid; o < P_ * D_; o += 256){
        int d = o & 127, p = o >> 7;
        float a = tb2[p];
        #pragma unroll
        for (int t = 0; t < TH_; t++) a = fmaf(sh[d][t], tW2[t * P_ + p], a);
        mb[p * D_ + d] += a;
    }
}

// ---------------- mixer: channel mixing (16 rows per block) ----------------
__global__ __launch_bounds__(256)
void k_channel_mix(float* __restrict__ m, const float* __restrict__ g, const float* __restrict__ be,
                   const float* __restrict__ cW1, const float* __restrict__ cb1,
                   const float* __restrict__ cW2, const float* __restrict__ cb2){
    __shared__ float sy[16][D_];        // 8 KB
    __shared__ float sh[16][CH_ + 1];   // 32.8 KB
    int r0 = blockIdx.x * 16, tid = threadIdx.x;
    int wv = tid >> 6, ln_ = tid & 63;
    for (int r = wv; r < 16; r += 4){
        float v0 = m[(long)(r0 + r) * D_ + ln_], v1 = m[(long)(r0 + r) * D_ + 64 + ln_];
        float s = v0 + v1, ss = v0 * v0 + v1 * v1;
        #pragma unroll
        for (int o = 32; o > 0; o >>= 1){ s += __shfl_down(s, o, 64); ss += __shfl_down(ss, o, 64); }
        s = __shfl(s, 0, 64); ss = __shfl(ss, 0, 64);
        float mu = s * (1.f / 128.f);
        float var = ss * (1.f / 128.f) - mu * mu;
        float rs = rsqrtf(var + 1e-5f);
        sy[r][ln_]      = (v0 - mu) * rs * g[ln_]      + be[ln_];
        sy[r][64 + ln_] = (v1 - mu) * rs * g[64 + ln_] + be[64 + ln_];
    }
    __syncthreads();
    #pragma unroll
    for (int th = 0; th < 2; th++){
        int t = tid + th * 256;
        float acc[16];
        #pragma unroll
        for (int r = 0; r < 16; r++) acc[r] = cb1[t];
        for (int k = 0; k < D_; k++){
            float w = cW1[k * CH_ + t];
            #pragma unroll
            for (int r = 0; r < 16; r++) acc[r] = fmaf(sy[r][k], w, acc[r]);
        }
        #pragma unroll
        for (int r = 0; r < 16; r++) sh[r][t] = gelu_t(acc[r]);
    }
    __syncthreads();
    {
        int d = tid & 127, rbase = tid >> 7;
        float acc[8];
        #pragma unroll
        for (int q = 0; q < 8; q++) acc[q] = 0.f;
        for (int t = 0; t < CH_; t++){
            float w = cW2[t * D_ + d];
            #pragma unroll
            for (int q = 0; q < 8; q++) acc[q] = fmaf(sh[rbase + 2 * q][t], w, acc[q]);
        }
        float cb = cb2[d];
        #pragma unroll
        for (int q = 0; q < 8; q++){
            int row = r0 + rbase + 2 * q;
            m[(long)row * D_ + d] += acc[q] + cb;
        }
    }
}

// ---------------- final pooled head ----------------
__global__ __launch_bounds__(128)
void k_final(const float* __restrict__ m, const float* __restrict__ oW1, const float* __restrict__ ob1,
             const float* __restrict__ oW2, const float* __restrict__ ob2, float* __restrict__ out){
    __shared__ float sp[D_];
    __shared__ float red[128];
    int b = blockIdx.x, tid = threadIdx.x;
    float a = 0.f;
    for (int p = 0; p < P_; p++) a += m[(long)b * P_ * D_ + p * D_ + tid];
    sp[tid] = a * (1.0f / P_);
    __syncthreads();
    float h = ob1[tid];
    for (int d = 0; d < D_; d++) h = fmaf(sp[d], oW1[d * D_ + tid], h);
    h = fmaxf(h, 0.f) * oW2[tid];
    red[tid] = h;
    __syncthreads();
    for (int s = 64; s > 0; s >>= 1){
        if (tid < s) red[tid] += red[tid + s];
        __syncthreads();
    }
    if (tid == 0) out[b] = red[0] + ob2[0];
}

extern "C" void kernel_launch(void* const* d_in, const int* in_sizes, int n_in,
                              void* d_out, int out_size, void* d_ws, size_t ws_size,
                              hipStream_t stream){
    const int*   x_atom       = (const int*)  d_in[0];
    const float* rw_pe        = (const float*)d_in[1];
    const int*   edge_attr    = (const int*)  d_in[2];
    const int*   nodes_mapper = (const int*)  d_in[3];
    const int*   edges_mapper = (const int*)  d_in[4];
    const int*   edge_index   = (const int*)  d_in[5];
    const int*   batch_x      = (const int*)  d_in[6];
    const float* patch_pe     = (const float*)d_in[7];
    // d_in[8] = mask, all-true by construction -> mean pooling
    const float* atom_emb = (const float*)d_in[9];
    const float* bond_emb = (const float*)d_in[10];
    const float* rw_W  = (const float*)d_in[11];
    const float* rw_b  = (const float*)d_in[12];
    const float* prw_W = (const float*)d_in[13];
    const float* prw_b = (const float*)d_in[14];
    const float* gnn_W = (const float*)d_in[15];
    const float* gnn_b = (const float*)d_in[16];
    const float* U_W   = (const float*)d_in[17];
    const float* U_b   = (const float*)d_in[18];
    const float* ln1_g = (const float*)d_in[19];
    const float* ln1_b = (const float*)d_in[20];
    const float* tW1   = (const float*)d_in[21];
    const float* tb1   = (const float*)d_in[22];
    const float* tW2   = (const float*)d_in[23];
    const float* tb2   = (const float*)d_in[24];
    const float* ln2_g = (const float*)d_in[25];
    const float* ln2_b = (const float*)d_in[26];
    const float* cW1   = (const float*)d_in[27];
    const float* cb1   = (const float*)d_in[28];
    const float* cW2   = (const float*)d_in[29];
    const float* cb2   = (const float*)d_in[30];
    const float* oW1   = (const float*)d_in[31];
    const float* ob1   = (const float*)d_in[32];
    const float* oW2   = (const float*)d_in[33];
    const float* ob2   = (const float*)d_in[34];

    const int* srcv = edge_index;
    const int* dstv = edge_index + ES_;

    // ---- workspace layout: ~202.4 MB <= 256 MiB ----
    char* w = (char*)d_ws;
    size_t offXS  = 0;                                        // per-copy state [NS,128] bf16 (patch-major)
    size_t offXN  = offXS  + (size_t)NS_ * D_ * 2;            // compact [N,128] bf16
    size_t offRP  = offXN  + (size_t)N_ORIG * D_ * 2;
    size_t offEP  = offRP  + 2000064;
    size_t offPRP = offEP  + (size_t)ES_ * 4;
    size_t offNRP = offPRP + 32832;
    size_t offNL  = offNRP + 800064;
    size_t offPERM= offNL  + (size_t)NS_ * 4;
    size_t offBX2 = offPERM+ (size_t)NS_ * 4;
    size_t offNM2 = offBX2 + (size_t)NS_ * 4;
    size_t offBS  = offNM2 + (size_t)NS_ * 4;
    size_t offPM  = offBS  + 2048;
    size_t offST  = offPM  + (size_t)BP_ * D_ * 2;
    size_t offM   = offST  + (size_t)BP_ * D_ * 2;
    size_t needed = offM   + (size_t)BP_ * D_ * 4;

    if (ws_size < needed){
        k_breadcrumb<<<cdiv_l(out_size, 256), 256, 0, stream>>>((float*)d_out, out_size,
                                                                (float)(ws_size >> 20));
        return;
    }

    // canary: absmax ~6.7 -> pipeline died mid-way; ~0.32 -> module never ran
    k_breadcrumb<<<cdiv_l(out_size, 256), 256, 0, stream>>>((float*)d_out, out_size, 7.0f);

    ushort_t* xs = (ushort_t*)(w + offXS);
    ushort_t* xn = (ushort_t*)(w + offXN);
    int* rp    = (int*)(w + offRP);
    int* ep    = (int*)(w + offEP);
    int* prp   = (int*)(w + offPRP);
    int* nrp   = (int*)(w + offNRP);
    int* nlist = (int*)(w + offNL);
    int* perm  = (int*)(w + offPERM);
    int* bx2   = (int*)(w + offBX2);
    int* nm2   = (int*)(w + offNM2);
    int* bsum  = (int*)(w + offBS);
    ushort_t* pm   = (ushort_t*)(w + offPM);
    ushort_t* subT = (ushort_t*)(w + offST);
    float*    mbuf = (float*)(w + offM);
    // cursors borrow xs (dead until conv 0 writes it)
    int* cur_e = (int*)(w + offXS);
    int* cur_p = (int*)(w + offXS + 4194304);
    int* cur_n = (int*)(w + offXS + 8388608);

    const int TPB = 256;

    // ---- patch & node degree histograms, scans ----
    hipMemsetAsync(prp, 0, 32832, stream);
    hipMemsetAsync(nrp, 0, 800064, stream);
    k_deg_ns<<<cdiv_l(NS_, TPB), TPB, 0, stream>>>(batch_x, nodes_mapper, prp, nrp);
    k_scan1<<<cdiv_l(BP_, 1024), TPB, 0, stream>>>(prp, bsum, BP_);
    k_scan2<<<1, 512, 0, stream>>>(bsum, cdiv_l(BP_, 1024));
    k_scan3<<<cdiv_l(BP_ + 1, TPB), TPB, 0, stream>>>(prp, bsum, cur_p, BP_, NS_);
    k_scan1<<<cdiv_l(N_ORIG, 1024), TPB, 0, stream>>>(nrp, bsum, N_ORIG);
    k_scan2<<<1, 512, 0, stream>>>(bsum, cdiv_l(N_ORIG, 1024));
    k_scan3<<<cdiv_l(N_ORIG + 1, TPB), TPB, 0, stream>>>(nrp, bsum, cur_n, N_ORIG, NS_);
    // ---- relabeling scatter (perm/bx2/nm2/nlist) ----
    k_scatter_ns<<<cdiv_l(NS_, TPB), TPB, 0, stream>>>(batch_x, nodes_mapper, cur_p, cur_n,
                                                       perm, bx2, nm2, nlist);
    // ---- edge CSR over relabeled dst ----
    hipMemsetAsync(rp, 0, 2000064, stream);
    k_deg_edges<<<cdiv_l(ES_, TPB), TPB, 0, stream>>>(dstv, perm, rp);
    k_scan1<<<cdiv_l(NS_, 1024), TPB, 0, stream>>>(rp, bsum, NS_);
    k_scan2<<<1, 512, 0, stream>>>(bsum, cdiv_l(NS_, 1024));
    k_scan3<<<cdiv_l(NS_ + 1, TPB), TPB, 0, stream>>>(rp, bsum, cur_e, NS_, ES_);
    k_scatter_edges<<<cdiv_l(ES_, TPB), TPB, 0, stream>>>(srcv, dstv, edge_attr, edges_mapper,
                                                          nodes_mapper, perm, cur_e, ep);

    // ---- encode (compact, N rows) ----
    k_encode<<<cdiv_l((long)N_ORIG * 32, TPB), TPB, 0, stream>>>(x_atom, rw_pe, atom_emb,
                                                                 rw_W, rw_b, xn);

    for (int i = 0; i < 4; i++){
        if (i > 0){
            k_patch_pool<<<BP_, 128, 0, stream>>>(xs, prp, pm);
            k_gemm128<<<512, TPB, 0, stream>>>(pm, U_W + (i - 1) * D_ * D_,
                                               U_b + (i - 1) * D_, subT, BP_);
            k_node_resync<<<N_ORIG, 128, 0, stream>>>(xs, subT, bx2, nrp, nlist, xn);
        }
        k_conv_mfma<<<2048, TPB, 0, stream>>>(xn, nm2, xs, rp, ep, bond_emb,
                                              gnn_W + i * D_ * D_, gnn_b + i * D_);
    }

    // ---- patch pooling + mixer ----
    k_patch_pool_sx<<<BP_, 128, 0, stream>>>(xs, prp, patch_pe, prw_W, prw_b, mbuf);

    for (int l = 0; l < 2; l++){
        k_token_mix<<<B_, TPB, 0, stream>>>(mbuf, ln1_g + l * D_, ln1_b + l * D_,
                                            tW1 + l * P_ * TH_, tb1 + l * TH_,
                                            tW2 + l * TH_ * P_, tb2 + l * P_);
        k_channel_mix<<<BP_ / 16, TPB, 0, stream>>>(mbuf, ln2_g + l * D_, ln2_b + l * D_,
                                                    cW1 + l * D_ * CH_, cb1 + l * CH_,
                                                    cW2 + l * CH_ * D_, cb2 + l * D_);
    }
    k_final<<<B_, 128, 0, stream>>>(mbuf, oW1, ob1, oW2, ob2, (float*)d_out);
}